// Round 5
// baseline (3536.317 us; speedup 1.0000x reference)
//
#include <hip/hip_runtime.h>
#include <math.h>

#define BATCH 4
#define HH 512
#define WW 1024
#define NPIX (HH*WW)          // 524288 = 2^19
#define CCAP 196608           // compaction capacity per image (expected ~161.7k valid)
#define GX 128
#define GY 96
#define NCELL (GX*GY)         // 12288 cells, 0.03125 x 0.03125 over [-1,3]x[-1,2]
#define CELL 0.03125f
#define INVCELL 32.0f
#define CPT (NCELL/1024)      // cells per thread in scan

// ---------------- XLA:CPU f32 math replicas (unchanged from passing rounds) ----
__device__ __forceinline__ float xla_tanhf(float x) {
  if (fabsf(x) < 0.0004f) return x;
  float xc = fminf(fmaxf(x, -7.90531110763549805f), 7.90531110763549805f);
  float x2 = __fmul_rn(xc, xc);
  float p = -2.76076847742355e-16f;
  p = fmaf(x2, p, 2.00018790482477e-13f);
  p = fmaf(x2, p, -8.60467152213735e-11f);
  p = fmaf(x2, p, 5.12229709037114e-08f);
  p = fmaf(x2, p, 1.48572235717979e-05f);
  p = fmaf(x2, p, 6.37261928875436e-04f);
  p = fmaf(x2, p, 4.89352455891786e-03f);
  p = __fmul_rn(xc, p);
  float q = fmaf(x2, 1.19825839466702e-06f, 1.18534705686654e-04f);
  q = fmaf(x2, q, 2.26843463243900e-03f);
  q = fmaf(x2, q, 4.89352518554385e-03f);
  return __fdiv_rn(p, q);
}

__device__ __forceinline__ float xla_expf(float x) {
  float xc = fminf(fmaxf(x, -87.3365478515625f), 88.72283935546875f);
  float m = floorf(fmaf(xc, 1.44269504088896341f, 0.5f));
  float r = fmaf(m, -0.693359375f, xc);
  r = fmaf(m, 2.12194440e-4f, r);
  float r2 = __fmul_rn(r, r);
  float p = 1.9875691500e-4f;
  p = fmaf(p, r, 1.3981999507e-3f);
  p = fmaf(p, r, 8.3334519073e-3f);
  p = fmaf(p, r, 4.1665795894e-2f);
  p = fmaf(p, r, 1.6666665459e-1f);
  p = fmaf(p, r, 5.0000001201e-1f);
  float y = fmaf(r2, p, r);
  y = __fadd_rn(y, 1.0f);
  return ldexpf(y, (int)m);
}

__device__ __forceinline__ float xla_sigmoidf(float x) {
  return fmaf(0.5f, xla_tanhf(__fmul_rn(0.5f, x)), 0.5f);
}

// Proposal test — byte-identical decision logic to the passing kernels.
__device__ __forceinline__ bool prop_test(float2 e, float cx, float cy,
                                          float den0, float den1,
                                          float inv0, float inv1) {
  float d0 = __fsub_rn(e.x, cx), d1 = __fsub_rn(e.y, cy);
  float dd0 = __fmul_rn(d0, d0), dd1 = __fmul_rn(d1, d1);
  float zf = fmaf(dd0, inv0, __fmul_rn(dd1, inv1));
  if (zf < 0.6921472f) return true;
  if (zf <= 0.6941472f) {
    float t0 = __fdiv_rn(dd0, den0);
    float t1 = __fdiv_rn(dd1, den1);
    float z = __fadd_rn(t0, t1);
    return xla_expf(-z) > 0.5f;
  }
  return false;
}

__device__ __forceinline__ int cell_of_x(float ex) {
  int c = (int)((ex + 1.0f) * INVCELL);
  return min(max(c, 0), GX - 1);
}
__device__ __forceinline__ int cell_of_y(float ey) {
  int c = (int)((ey + 1.0f) * INVCELL);
  return min(max(c, 0), GY - 1);
}

// Per-row geometry: outer proposal-possible col range [c0,c1] (conservative-wide,
// same math as the passing round-4 kernel) and interior all-proposed col run
// [ci0,ci1] (conservative-narrow; misclassification only moves cells to the
// per-pixel path).
struct RowG { int c0, c1, ci0, ci1; bool any; };

__device__ __forceinline__ RowG row_geom(int r, float cx, float cy,
                                         float den0, float inv1) {
  RowG g; g.any = false; g.ci0 = 1; g.ci1 = 0;
  float ylo = fmaf((float)r, CELL, -1.0f);
  float yhi = ylo + CELL;
  float dy = fmaxf(0.0f, fmaxf(ylo - cy, cy - yhi)) * 0.999999f;
  float rem = 0.6971472f - dy * dy * inv1;
  if (rem <= 0.0f) return g;
  g.any = true;
  float dxm = sqrtf(den0 * rem) * 1.00001f;
  g.c0 = cell_of_x(cx - dxm);
  g.c1 = cell_of_x(cx + dxm);
  float dyc = fmaxf(fabsf(ylo - cy), fabsf(yhi - cy)) + 1e-5f;
  float remI = 0.6920f - dyc * dyc * inv1;
  if (remI > 0.0f) {
    float dxin = sqrtf(den0 * remI) * 0.9999f;
    int a = (int)ceilf(fmaf(cx - dxin, INVCELL, INVCELL) + 1e-3f);
    int b2 = (int)floorf(fmaf(cx + dxin, INVCELL, INVCELL) - 1e-3f) - 1;
    a = max(a, g.c0); b2 = min(b2, g.c1);
    g.ci0 = a; g.ci1 = b2;
  }
  return g;
}

// Boundary range: per-pixel prop_test, wave-ballot-aggregated word updates.
__device__ __forceinline__ void bnd_range(int lo, int hi, int tid, int lane,
    const float2* __restrict__ emb, float cx, float cy, float den0, float den1,
    float inv0, float inv1, unsigned* s_uncl, int* s_dirty, int &pc, int &uc) {
  for (int i0 = lo + (tid & ~63); i0 < hi; i0 += 1024) {
    int i = i0 + lane;
    bool p = (i < hi) && prop_test(emb[i], cx, cy, den0, den1, inv0, inv1);
    unsigned long long mask = __ballot(p);
    if (mask == 0ULL) continue;
    int off = i0 & 31;
    unsigned w = (unsigned)(i0 >> 5);
    unsigned bits = 0; unsigned tw = w;
    if (lane == 0) { pc += (int)__popcll(mask); bits = (unsigned)(mask << off); }
    else if (lane == 1) { bits = (unsigned)(mask >> (32 - off)); tw = w + 1; }
    else if (lane == 2 && off > 0) { bits = (unsigned)(mask >> (64 - off)); tw = w + 2; }
    if (bits) {
      unsigned old = atomicAnd(&s_uncl[tw], ~bits);
      unsigned remv = old & bits;
      if (remv) { uc += __popc(remv); s_dirty[tw >> 1] = 1; }
    }
  }
}

// Interior range: every pixel proposed — pure word ops, no loads, no prop_test.
__device__ __forceinline__ void int_range(int lo, int hi, int tid,
    unsigned* s_uncl, int* s_dirty, int &pc, int &uc) {
  if (lo >= hi) return;
  int wlo = lo >> 5, whi = (hi - 1) >> 5;
  for (int w = wlo + tid; w <= whi; w += 1024) {
    unsigned m = 0xffffffffu;
    if (w == wlo) m &= (0xffffffffu << (lo & 31));
    if (w == whi) { int t = hi - (whi << 5); if (t < 32) m &= ((1u << t) - 1u); }
    pc += __popc(m);
    unsigned old = atomicAnd(&s_uncl[w], ~m);
    unsigned remv = old & m;
    if (remv) { uc += __popc(remv); s_dirty[w >> 1] = 1; }
  }
}

// ---------------- kernels ----------------

__global__ __launch_bounds__(1024) void fill_kernel(int* out, int val, int n) {
  int i = blockIdx.x * 1024 + threadIdx.x;
  if (i < n) out[i] = val;
}

__global__ __launch_bounds__(256) void hist_kernel(const float* __restrict__ in,
                                                   int* __restrict__ out,
                                                   int* __restrict__ hist) {
  int gid = blockIdx.x * 256 + threadIdx.x;
  int b = gid >> 19;
  int p = gid & (NPIX - 1);
  const float* base = in + (size_t)b * 5 * NPIX;
  float seed = base[(size_t)4 * NPIX + p];
  out[gid] = 0;
  if (seed > 0.5f) {
    float ox = base[p];
    float oy = base[(size_t)NPIX + p];
    int col = p & (WW - 1);
    int row = p >> 10;
    float gx = __fmul_rn((float)col, 2.0f / 1023.0f);
    float gy = __fmul_rn((float)row, 1.0f / 511.0f);
    float ex = __fadd_rn(xla_tanhf(ox), gx);
    float ey = __fadd_rn(xla_tanhf(oy), gy);
    atomicAdd(&hist[b * NCELL + cell_of_y(ey) * GX + cell_of_x(ex)], 1);
  }
}

__global__ __launch_bounds__(1024) void scan_kernel(const int* __restrict__ hist,
                                                    int* __restrict__ off,
                                                    int* __restrict__ cursor) {
  __shared__ int s_c[NCELL];
  __shared__ int s_ps[1024];
  int b = blockIdx.x, t = threadIdx.x;
  const int* h = hist + b * NCELL;
  for (int i = t; i < NCELL; i += 1024) s_c[i] = h[i];
  __syncthreads();
  int v[CPT]; int th = 0;
  #pragma unroll
  for (int j = 0; j < CPT; ++j) { v[j] = s_c[CPT * t + j]; th += v[j]; }
  s_ps[t] = th;
  __syncthreads();
  for (int d = 1; d < 1024; d <<= 1) {
    int x = (t >= d) ? s_ps[t - d] : 0;
    __syncthreads();
    s_ps[t] += x;
    __syncthreads();
  }
  int excl = s_ps[t] - th;
  int* ob = off + b * (NCELL + 1);
  int* cb = cursor + b * NCELL;
  #pragma unroll
  for (int j = 0; j < CPT; ++j) {
    ob[CPT * t + j] = excl; cb[CPT * t + j] = excl; excl += v[j];
  }
  if (t == 1023) ob[NCELL] = s_ps[1023];
}

__global__ __launch_bounds__(256) void scatter_kernel(const float* __restrict__ in,
                                                      int* __restrict__ cursor,
                                                      float2* __restrict__ emb,
                                                      int2* __restrict__ pk) {
  int gid = blockIdx.x * 256 + threadIdx.x;
  int b = gid >> 19;
  int p = gid & (NPIX - 1);
  const float* base = in + (size_t)b * 5 * NPIX;
  float seed = base[(size_t)4 * NPIX + p];
  if (seed > 0.5f) {
    float ox = base[p];
    float oy = base[(size_t)NPIX + p];
    int col = p & (WW - 1);
    int row = p >> 10;
    float gx = __fmul_rn((float)col, 2.0f / 1023.0f);
    float gy = __fmul_rn((float)row, 1.0f / 511.0f);
    float ex = __fadd_rn(xla_tanhf(ox), gx);
    float ey = __fadd_rn(xla_tanhf(oy), gy);
    float smv = xla_sigmoidf(seed);
    int cell = cell_of_y(ey) * GX + cell_of_x(ex);
    int slot = atomicAdd(&cursor[b * NCELL + cell], 1);
    if (slot < CCAP) {
      emb[(size_t)b * CCAP + slot] = make_float2(ex, ey);
      pk[(size_t)b * CCAP + slot]  = make_int2(__float_as_int(smv), p);
    }
  }
}

// One workgroup per image. 3 barriers/iteration.
__global__ __launch_bounds__(1024) void cluster_kernel(const float* __restrict__ in,
                                                       int* __restrict__ out,
                                                       const float2* __restrict__ emb_all,
                                                       const int2* __restrict__ pk_all,
                                                       const int* __restrict__ off_g) {
  __shared__ unsigned int s_uncl[CCAP / 32];            // 24 KB
  __shared__ int s_off[NCELL + 1];                      // 48 KB
  __shared__ unsigned long long s_segkey[CCAP / 64];    // 24 KB
  __shared__ int s_dirty[CCAP / 64];                    // 12 KB
  __shared__ unsigned long long s_bestkey[2];
  __shared__ int s_pc[2];
  __shared__ int s_uc[2];

  int b = blockIdx.x;
  int tid = threadIdx.x;
  int lane = tid & 63;
  int wid = tid >> 6;
  const int* offb = off_g + b * (NCELL + 1);
  int V = offb[NCELL];
  const float2* emb = emb_all + (size_t)b * CCAP;
  const int2*   pk  = pk_all  + (size_t)b * CCAP;
  int* outb = out + (size_t)b * NPIX;
  const float* base = in + (size_t)b * 5 * NPIX;

  if (V > CCAP) {   // capacity overflow marker
    for (int i = tid; i < NPIX; i += 1024) outb[i] = 1000000;
    return;
  }
  int NSEG = (V + 63) >> 6;

  for (int i = tid; i <= NCELL; i += 1024) s_off[i] = offb[i];
  for (int w = tid; w < CCAP / 32; w += 1024) {
    int basebit = w << 5;
    unsigned m;
    if (basebit + 32 <= V)      m = 0xffffffffu;
    else if (basebit >= V)      m = 0u;
    else                        m = (1u << (V - basebit)) - 1u;
    s_uncl[w] = m;
  }
  for (int s = tid; s < CCAP / 64; s += 1024) s_dirty[s] = 0;
  if (tid < 2) { s_bestkey[tid] = 0ULL; s_pc[tid] = 0; s_uc[tid] = 0; }
  __syncthreads();

  // build segment keys (all pixels unclustered initially)
  for (int s = wid; s < NSEG; s += 16) {
    int i = (s << 6) + lane;
    unsigned long long k = 0ULL;
    if (i < V) {
      int2 v = pk[i];
      k = ((unsigned long long)(unsigned)v.x << 32) | (unsigned)(~v.y);
    }
    for (int o = 32; o > 0; o >>= 1) {
      unsigned long long ok = __shfl_down(k, o);
      if (ok > k) k = ok;
    }
    if (lane == 0) s_segkey[s] = k;
  }
  __syncthreads();

  // initial argmax into slot 0
  {
    unsigned long long k = 0ULL;
    for (int s = tid; s < NSEG; s += 1024) {
      unsigned long long v = s_segkey[s];
      if (v > k) k = v;
    }
    for (int o = 32; o > 0; o >>= 1) {
      unsigned long long ok = __shfl_down(k, o);
      if (ok > k) k = ok;
    }
    if (lane == 0) atomicMax(&s_bestkey[0], k);
  }
  __syncthreads();

  int ucount = V, count = 1, guard = 0;
  int t = 0;
  while (ucount > 64 && guard++ <= CCAP) {
    int cur = t & 1, nxt = cur ^ 1;
    unsigned long long key = s_bestkey[cur];
    if (key == 0ULL) break;
    float sm = __uint_as_float((unsigned)(key >> 32));
    if (sm < 0.5f) break;              // ref's new_done (provably never fires)
    int px = (int)(~(unsigned)key);

    // ---- phase A: all threads redundantly compute center params (broadcast loads) ----
    float ox = base[px];
    float oy = base[(size_t)NPIX + px];
    float sx = base[(size_t)2 * NPIX + px];
    float sy = base[(size_t)3 * NPIX + px];
    int scol = px & (WW - 1);
    int srow = px >> 10;
    float cgx = __fmul_rn((float)scol, 2.0f / 1023.0f);
    float cgy = __fmul_rn((float)srow, 1.0f / 511.0f);
    float cx = __fadd_rn(xla_tanhf(ox), cgx);    // bit-identical to scatter's emb
    float cy = __fadd_rn(xla_tanhf(oy), cgy);
    float den0 = __fmul_rn(2.0f, __fmul_rn(sx, sx));
    float den1 = __fmul_rn(2.0f, __fmul_rn(sy, sy));
    float inv0 = 1.0f / den0;
    float inv1 = 1.0f / den1;
    float ry = sqrtf(__fmul_rn(den1, 0.6971472f)) * 1.00001f;
    int r0 = cell_of_y(cy - ry);
    int r1 = cell_of_y(cy + ry);

    // ---- pass 1: proposal count + removal, interior runs via word ops ----
    int pc = 0, uc = 0;
    for (int r = r0; r <= r1; ++r) {
      RowG g = row_geom(r, cx, cy, den0, inv1);
      if (!g.any) continue;
      int rb = r * GX;
      int lo = s_off[rb + g.c0], hi = s_off[rb + g.c1 + 1];
      if (g.ci0 <= g.ci1) {
        int m0 = s_off[rb + g.ci0], m1 = s_off[rb + g.ci1 + 1];
        bnd_range(lo, m0, tid, lane, emb, cx, cy, den0, den1, inv0, inv1,
                  s_uncl, s_dirty, pc, uc);
        int_range(m0, m1, tid, s_uncl, s_dirty, pc, uc);
        bnd_range(m1, hi, tid, lane, emb, cx, cy, den0, den1, inv0, inv1,
                  s_uncl, s_dirty, pc, uc);
      } else {
        bnd_range(lo, hi, tid, lane, emb, cx, cy, den0, den1, inv0, inv1,
                  s_uncl, s_dirty, pc, uc);
      }
    }
    for (int o = 32; o > 0; o >>= 1) {
      pc += __shfl_down(pc, o);
      uc += __shfl_down(uc, o);
    }
    if (lane == 0 && (pc | uc)) {
      if (pc) atomicAdd(&s_pc[cur], pc);
      if (uc) atomicAdd(&s_uc[cur], uc);
    }
    __syncthreads();   // B1

    int pcT = s_pc[cur];
    int ucR = s_uc[cur];            // total removed this iter (includes seed)
    bool accept = (pcT > 64) && (2 * (ucR - 1) > pcT);  // ref uc excludes seed
    int label = count & 255;
    if (accept) count++;
    ucount -= ucR;
    if (tid == 0) { s_pc[nxt] = 0; s_uc[nxt] = 0; s_bestkey[nxt] = 0ULL; }

    // ---- labels (rare: only accepted iterations) ----
    if (accept) {
      for (int r = r0; r <= r1; ++r) {
        RowG g = row_geom(r, cx, cy, den0, inv1);
        if (!g.any) continue;
        int rb = r * GX;
        int lo = s_off[rb + g.c0], hi = s_off[rb + g.c1 + 1];
        int m0 = lo, m1 = lo;
        if (g.ci0 <= g.ci1) { m0 = s_off[rb + g.ci0]; m1 = s_off[rb + g.ci1 + 1]; }
        for (int i = lo + tid; i < m0; i += 1024)
          if (prop_test(emb[i], cx, cy, den0, den1, inv0, inv1)) outb[pk[i].y] = label;
        for (int i = m0 + tid; i < m1; i += 1024) outb[pk[i].y] = label;
        for (int i = m1 + tid; i < hi; i += 1024)
          if (prop_test(emb[i], cx, cy, den0, den1, inv0, inv1)) outb[pk[i].y] = label;
      }
    }

    // ---- dirty segment rescans (wave-owned: strided by 16) ----
    for (int r = r0; r <= r1; ++r) {
      RowG g = row_geom(r, cx, cy, den0, inv1);
      if (!g.any) continue;
      int rb = r * GX;
      int lo = s_off[rb + g.c0], hi = s_off[rb + g.c1 + 1];
      if (hi <= lo) continue;
      int slo = lo >> 6, shi = (hi - 1) >> 6;
      for (int s = slo + ((wid - slo) & 15); s <= shi; s += 16) {
        if (s_dirty[s]) {
          if (lane == 0) s_dirty[s] = 0;
          int i = (s << 6) + lane;
          unsigned long long k = 0ULL;
          if (i < V && ((s_uncl[i >> 5] >> (i & 31)) & 1u)) {
            int2 v = pk[i];
            k = ((unsigned long long)(unsigned)v.x << 32) | (unsigned)(~v.y);
          }
          for (int o = 32; o > 0; o >>= 1) {
            unsigned long long ok = __shfl_down(k, o);
            if (ok > k) k = ok;
          }
          if (lane == 0) s_segkey[s] = k;
        }
      }
    }
    __syncthreads();   // B2

    // ---- argmax over segment keys into next slot ----
    {
      unsigned long long k = 0ULL;
      for (int s = tid; s < NSEG; s += 1024) {
        unsigned long long v = s_segkey[s];
        if (v > k) k = v;
      }
      for (int o = 32; o > 0; o >>= 1) {
        unsigned long long ok = __shfl_down(k, o);
        if (ok > k) k = ok;
      }
      if (lane == 0) atomicMax(&s_bestkey[nxt], k);
    }
    __syncthreads();   // B3
    t++;
  }
}

// ---------------- launch ----------------

extern "C" void kernel_launch(void* const* d_in, const int* in_sizes, int n_in,
                              void* d_out, int out_size, void* d_ws, size_t ws_size,
                              hipStream_t stream) {
  const float* in = (const float*)d_in[0];
  int* out = (int*)d_out;

  size_t hist_bytes = (size_t)BATCH * NCELL * sizeof(int);
  size_t off_bytes  = (size_t)BATCH * (NCELL + 1) * sizeof(int);
  size_t cur_bytes  = (size_t)BATCH * NCELL * sizeof(int);
  size_t emb_bytes  = (size_t)BATCH * CCAP * sizeof(float2);
  size_t pk_bytes   = (size_t)BATCH * CCAP * sizeof(int2);

  size_t o_hist = 256;
  size_t o_off  = (o_hist + hist_bytes + 255) & ~(size_t)255;
  size_t o_cur  = (o_off + off_bytes + 255) & ~(size_t)255;
  size_t o_emb  = (o_cur + cur_bytes + 255) & ~(size_t)255;
  size_t o_pk   = (o_emb + emb_bytes + 255) & ~(size_t)255;
  size_t need   = o_pk + pk_bytes;

  if (ws_size < need) {
    fill_kernel<<<(out_size + 1023) / 1024, 1024, 0, stream>>>(out, 2000000, out_size);
    return;
  }

  int*    hist = (int*)((char*)d_ws + o_hist);
  int*    off  = (int*)((char*)d_ws + o_off);
  int*    cur  = (int*)((char*)d_ws + o_cur);
  float2* emb  = (float2*)((char*)d_ws + o_emb);
  int2*   pk   = (int2*)((char*)d_ws + o_pk);

  hipMemsetAsync(hist, 0, hist_bytes, stream);
  hist_kernel<<<(BATCH * NPIX) / 256, 256, 0, stream>>>(in, out, hist);
  scan_kernel<<<BATCH, 1024, 0, stream>>>(hist, off, cur);
  scatter_kernel<<<(BATCH * NPIX) / 256, 256, 0, stream>>>(in, cur, emb, pk);
  cluster_kernel<<<BATCH, 1024, 0, stream>>>(in, out, emb, pk, off);
}

// Round 6
// 1124.092 us; speedup vs baseline: 3.1459x; 3.1459x over previous
//
#include <hip/hip_runtime.h>
#include <math.h>

#define BATCH 4
#define HH 512
#define WW 1024
#define NPIX (HH*WW)          // 524288 = 2^19
#define CCAP 196608           // compaction capacity per image (expected ~161.7k valid)
#define GX 64
#define GY 48
#define NCELL (GX*GY)         // 3072 cells, 0.0625 x 0.0625 over [-1,3]x[-1,2]
#define CELL 0.0625f
#define INVCELL 16.0f
#define DLCAP 2048            // dirty-segment list capacity

// ---------------- XLA:CPU f32 math replicas (unchanged from passing rounds) ----
__device__ __forceinline__ float xla_tanhf(float x) {
  if (fabsf(x) < 0.0004f) return x;
  float xc = fminf(fmaxf(x, -7.90531110763549805f), 7.90531110763549805f);
  float x2 = __fmul_rn(xc, xc);
  float p = -2.76076847742355e-16f;
  p = fmaf(x2, p, 2.00018790482477e-13f);
  p = fmaf(x2, p, -8.60467152213735e-11f);
  p = fmaf(x2, p, 5.12229709037114e-08f);
  p = fmaf(x2, p, 1.48572235717979e-05f);
  p = fmaf(x2, p, 6.37261928875436e-04f);
  p = fmaf(x2, p, 4.89352455891786e-03f);
  p = __fmul_rn(xc, p);
  float q = fmaf(x2, 1.19825839466702e-06f, 1.18534705686654e-04f);
  q = fmaf(x2, q, 2.26843463243900e-03f);
  q = fmaf(x2, q, 4.89352518554385e-03f);
  return __fdiv_rn(p, q);
}

__device__ __forceinline__ float xla_expf(float x) {
  float xc = fminf(fmaxf(x, -87.3365478515625f), 88.72283935546875f);
  float m = floorf(fmaf(xc, 1.44269504088896341f, 0.5f));
  float r = fmaf(m, -0.693359375f, xc);
  r = fmaf(m, 2.12194440e-4f, r);
  float r2 = __fmul_rn(r, r);
  float p = 1.9875691500e-4f;
  p = fmaf(p, r, 1.3981999507e-3f);
  p = fmaf(p, r, 8.3334519073e-3f);
  p = fmaf(p, r, 4.1665795894e-2f);
  p = fmaf(p, r, 1.6666665459e-1f);
  p = fmaf(p, r, 5.0000001201e-1f);
  float y = fmaf(r2, p, r);
  y = __fadd_rn(y, 1.0f);
  return ldexpf(y, (int)m);
}

__device__ __forceinline__ float xla_sigmoidf(float x) {
  return fmaf(0.5f, xla_tanhf(__fmul_rn(0.5f, x)), 0.5f);
}

// Proposal test — byte-identical decision logic to the passing kernels.
__device__ __forceinline__ bool prop_test(float2 e, float cx, float cy,
                                          float den0, float den1,
                                          float inv0, float inv1) {
  float d0 = __fsub_rn(e.x, cx), d1 = __fsub_rn(e.y, cy);
  float dd0 = __fmul_rn(d0, d0), dd1 = __fmul_rn(d1, d1);
  float zf = fmaf(dd0, inv0, __fmul_rn(dd1, inv1));
  if (zf < 0.6921472f) return true;
  if (zf <= 0.6941472f) {
    float t0 = __fdiv_rn(dd0, den0);
    float t1 = __fdiv_rn(dd1, den1);
    float z = __fadd_rn(t0, t1);
    return xla_expf(-z) > 0.5f;
  }
  return false;
}

__device__ __forceinline__ int cell_of_x(float ex) {
  int c = (int)((ex + 1.0f) * INVCELL);
  return min(max(c, 0), GX - 1);
}
__device__ __forceinline__ int cell_of_y(float ey) {
  int c = (int)((ey + 1.0f) * INVCELL);
  return min(max(c, 0), GY - 1);
}

// ---------------- kernels ----------------

__global__ __launch_bounds__(1024) void fill_kernel(int* out, int val, int n) {
  int i = blockIdx.x * 1024 + threadIdx.x;
  if (i < n) out[i] = val;
}

__global__ __launch_bounds__(256) void hist_kernel(const float* __restrict__ in,
                                                   int* __restrict__ out,
                                                   int* __restrict__ hist) {
  int gid = blockIdx.x * 256 + threadIdx.x;
  int b = gid >> 19;
  int p = gid & (NPIX - 1);
  const float* base = in + (size_t)b * 5 * NPIX;
  float seed = base[(size_t)4 * NPIX + p];
  out[gid] = 0;
  if (seed > 0.5f) {
    float ox = base[p];
    float oy = base[(size_t)NPIX + p];
    int col = p & (WW - 1);
    int row = p >> 10;
    float gx = __fmul_rn((float)col, 2.0f / 1023.0f);
    float gy = __fmul_rn((float)row, 1.0f / 511.0f);
    float ex = __fadd_rn(xla_tanhf(ox), gx);
    float ey = __fadd_rn(xla_tanhf(oy), gy);
    atomicAdd(&hist[b * NCELL + cell_of_y(ey) * GX + cell_of_x(ex)], 1);
  }
}

__global__ __launch_bounds__(1024) void scan_kernel(const int* __restrict__ hist,
                                                    int* __restrict__ off,
                                                    int* __restrict__ cursor) {
  __shared__ int s_c[NCELL];
  __shared__ int s_ps[1024];
  int b = blockIdx.x, t = threadIdx.x;
  const int* h = hist + b * NCELL;
  for (int i = t; i < NCELL; i += 1024) s_c[i] = h[i];
  __syncthreads();
  int a = s_c[3 * t], b2 = s_c[3 * t + 1], c2 = s_c[3 * t + 2];
  int th = a + b2 + c2;
  s_ps[t] = th;
  __syncthreads();
  for (int d = 1; d < 1024; d <<= 1) {
    int v = (t >= d) ? s_ps[t - d] : 0;
    __syncthreads();
    s_ps[t] += v;
    __syncthreads();
  }
  int excl = s_ps[t] - th;
  int* ob = off + b * (NCELL + 1);
  int* cb = cursor + b * NCELL;
  ob[3 * t] = excl;              cb[3 * t] = excl;
  ob[3 * t + 1] = excl + a;      cb[3 * t + 1] = excl + a;
  ob[3 * t + 2] = excl + a + b2; cb[3 * t + 2] = excl + a + b2;
  if (t == 1023) ob[NCELL] = s_ps[1023];
}

__global__ __launch_bounds__(256) void scatter_kernel(const float* __restrict__ in,
                                                      int* __restrict__ cursor,
                                                      float2* __restrict__ emb,
                                                      int2* __restrict__ pk) {
  int gid = blockIdx.x * 256 + threadIdx.x;
  int b = gid >> 19;
  int p = gid & (NPIX - 1);
  const float* base = in + (size_t)b * 5 * NPIX;
  float seed = base[(size_t)4 * NPIX + p];
  if (seed > 0.5f) {
    float ox = base[p];
    float oy = base[(size_t)NPIX + p];
    int col = p & (WW - 1);
    int row = p >> 10;
    float gx = __fmul_rn((float)col, 2.0f / 1023.0f);
    float gy = __fmul_rn((float)row, 1.0f / 511.0f);
    float ex = __fadd_rn(xla_tanhf(ox), gx);
    float ey = __fadd_rn(xla_tanhf(oy), gy);
    float smv = xla_sigmoidf(seed);
    int cell = cell_of_y(ey) * GX + cell_of_x(ex);
    int slot = atomicAdd(&cursor[b * NCELL + cell], 1);
    if (slot < CCAP) {
      emb[(size_t)b * CCAP + slot] = make_float2(ex, ey);
      pk[(size_t)b * CCAP + slot]  = make_int2(__float_as_int(smv), p);
    }
  }
}

// One workgroup per image. 3 barriers/iteration.
// Rows distributed to wave-PAIRS (pair = wid>>1, chunk parity = wid&1) so row
// scaffolding runs concurrently, not 16x-redundantly. Dirty segments collected
// in a deduped compact list during pass 1; rescan phase is O(dirty).
__global__ __launch_bounds__(1024) void cluster_kernel(const float* __restrict__ in,
                                                       int* __restrict__ out,
                                                       const float2* __restrict__ emb_all,
                                                       const int2* __restrict__ pk_all,
                                                       const int* __restrict__ off_g) {
  __shared__ unsigned int s_uncl[CCAP / 32];            // 24 KB
  __shared__ int s_off[NCELL + 1];                      // 12 KB
  __shared__ unsigned long long s_segkey[CCAP / 64];    // 24 KB
  __shared__ int s_dirty[CCAP / 64];                    // 12 KB
  __shared__ int s_dlist[DLCAP];                        // 8 KB
  __shared__ unsigned long long s_bestkey[2];
  __shared__ int s_pc[2];
  __shared__ int s_uc[2];
  __shared__ int s_nd[2];

  int b = blockIdx.x;
  int tid = threadIdx.x;
  int lane = tid & 63;
  int wid = tid >> 6;
  const int* offb = off_g + b * (NCELL + 1);
  int V = offb[NCELL];
  const float2* emb = emb_all + (size_t)b * CCAP;
  const int2*   pk  = pk_all  + (size_t)b * CCAP;
  int* outb = out + (size_t)b * NPIX;
  const float* base = in + (size_t)b * 5 * NPIX;

  if (V > CCAP) {   // capacity overflow marker
    for (int i = tid; i < NPIX; i += 1024) outb[i] = 1000000;
    return;
  }
  int NSEG = (V + 63) >> 6;

  for (int i = tid; i <= NCELL; i += 1024) s_off[i] = offb[i];
  for (int w = tid; w < CCAP / 32; w += 1024) {
    int basebit = w << 5;
    unsigned m;
    if (basebit + 32 <= V)      m = 0xffffffffu;
    else if (basebit >= V)      m = 0u;
    else                        m = (1u << (V - basebit)) - 1u;
    s_uncl[w] = m;
  }
  for (int s = tid; s < CCAP / 64; s += 1024) s_dirty[s] = 0;
  if (tid < 2) { s_bestkey[tid] = 0ULL; s_pc[tid] = 0; s_uc[tid] = 0; s_nd[tid] = 0; }
  __syncthreads();

  // build segment keys (all pixels unclustered initially)
  for (int s = wid; s < NSEG; s += 16) {
    int i = (s << 6) + lane;
    unsigned long long k = 0ULL;
    if (i < V) {
      int2 v = pk[i];
      k = ((unsigned long long)(unsigned)v.x << 32) | (unsigned)(~v.y);
    }
    for (int o = 32; o > 0; o >>= 1) {
      unsigned long long ok = __shfl_down(k, o);
      if (ok > k) k = ok;
    }
    if (lane == 0) s_segkey[s] = k;
  }
  __syncthreads();

  // initial argmax into slot 0
  {
    unsigned long long k = 0ULL;
    for (int s = tid; s < NSEG; s += 1024) {
      unsigned long long v = s_segkey[s];
      if (v > k) k = v;
    }
    for (int o = 32; o > 0; o >>= 1) {
      unsigned long long ok = __shfl_down(k, o);
      if (ok > k) k = ok;
    }
    if (lane == 0) atomicMax(&s_bestkey[0], k);
  }
  __syncthreads();

  int ucount = V, count = 1, guard = 0;
  int t = 0;
  while (ucount > 64 && guard++ <= CCAP) {
    int cur = t & 1, nxt = cur ^ 1;
    unsigned long long key = s_bestkey[cur];
    if (key == 0ULL) break;
    float sm = __uint_as_float((unsigned)(key >> 32));
    if (sm < 0.5f) break;              // ref's new_done (provably never fires)
    int px = (int)(~(unsigned)key);

    // ---- phase A: all threads redundantly compute center params (broadcast loads) ----
    float ox = base[px];
    float oy = base[(size_t)NPIX + px];
    float sx = base[(size_t)2 * NPIX + px];
    float sy = base[(size_t)3 * NPIX + px];
    int scol = px & (WW - 1);
    int srow = px >> 10;
    float cgx = __fmul_rn((float)scol, 2.0f / 1023.0f);
    float cgy = __fmul_rn((float)srow, 1.0f / 511.0f);
    float cx = __fadd_rn(xla_tanhf(ox), cgx);    // bit-identical to scatter's emb
    float cy = __fadd_rn(xla_tanhf(oy), cgy);
    float den0 = __fmul_rn(2.0f, __fmul_rn(sx, sx));
    float den1 = __fmul_rn(2.0f, __fmul_rn(sy, sy));
    float inv0 = 1.0f / den0;
    float inv1 = 1.0f / den1;
    float ry = sqrtf(__fmul_rn(den1, 0.6971472f)) * 1.00001f;
    int r0 = cell_of_y(cy - ry);
    int r1 = cell_of_y(cy + ry);
    int nr = r1 - r0 + 1;
    int pairid = wid >> 1;
    int chunk0 = (wid & 1) << 6;

    // ---- pass 1: proposal + count + removal + dirty-list build ----
    int pc = 0, uc = 0;
    for (int rr = pairid; rr < nr; rr += 8) {
      int r = r0 + rr;
      float ylo = fmaf((float)r, CELL, -1.0f);
      float dy = fmaxf(0.0f, fmaxf(ylo - cy, cy - (ylo + CELL))) * 0.999999f;
      float rem = 0.6971472f - dy * dy * inv1;
      if (rem <= 0.0f) continue;
      float dxm = sqrtf(den0 * rem) * 1.00001f;
      int c0 = cell_of_x(cx - dxm), c1 = cell_of_x(cx + dxm);
      int rs = s_off[r * GX + c0], re = s_off[r * GX + c1 + 1];
      for (int i0 = rs + chunk0; i0 < re; i0 += 128) {
        int i = i0 + lane;
        bool p = (i < re) && prop_test(emb[i], cx, cy, den0, den1, inv0, inv1);
        unsigned long long mask = __ballot(p);
        if (mask == 0ULL) continue;
        int off = i0 & 31;
        unsigned w = (unsigned)(i0 >> 5);
        unsigned bits = 0; unsigned tw = w;
        if (lane == 0) { pc += (int)__popcll(mask); bits = (unsigned)(mask << off); }
        else if (lane == 1) { bits = (unsigned)(mask >> (32 - off)); tw = w + 1; }
        else if (lane == 2 && off > 0) { bits = (unsigned)(mask >> (64 - off)); tw = w + 2; }
        if (bits) {
          unsigned old = atomicAnd(&s_uncl[tw], ~bits);
          unsigned remv = old & bits;
          if (remv) {
            uc += __popc(remv);
            int seg = (int)(tw >> 1);
            if (atomicExch(&s_dirty[seg], 1) == 0) {
              int pos = atomicAdd(&s_nd[cur], 1);
              if (pos < DLCAP) s_dlist[pos] = seg;
            }
          }
        }
      }
    }
    for (int o = 32; o > 0; o >>= 1) {
      pc += __shfl_down(pc, o);
      uc += __shfl_down(uc, o);
    }
    if (lane == 0 && (pc | uc)) {
      if (pc) atomicAdd(&s_pc[cur], pc);
      if (uc) atomicAdd(&s_uc[cur], uc);
    }
    __syncthreads();   // B1

    int pcT = s_pc[cur];
    int ucR = s_uc[cur];            // total removed this iter (includes seed)
    int ndRaw = s_nd[cur];
    bool accept = (pcT > 64) && (2 * (ucR - 1) > pcT);  // ref uc excludes seed
    int label = count & 255;
    if (accept) count++;
    ucount -= ucR;
    if (tid == 0) { s_pc[nxt] = 0; s_uc[nxt] = 0; s_bestkey[nxt] = 0ULL; s_nd[nxt] = 0; }

    // ---- labels (rare: only accepted iterations) ----
    if (accept) {
      for (int rr = pairid; rr < nr; rr += 8) {
        int r = r0 + rr;
        float ylo = fmaf((float)r, CELL, -1.0f);
        float dy = fmaxf(0.0f, fmaxf(ylo - cy, cy - (ylo + CELL))) * 0.999999f;
        float rem = 0.6971472f - dy * dy * inv1;
        if (rem <= 0.0f) continue;
        float dxm = sqrtf(den0 * rem) * 1.00001f;
        int c0 = cell_of_x(cx - dxm), c1 = cell_of_x(cx + dxm);
        int rs = s_off[r * GX + c0], re = s_off[r * GX + c1 + 1];
        for (int i = rs + chunk0 + lane; i < re; i += 128) {
          if (prop_test(emb[i], cx, cy, den0, den1, inv0, inv1)) {
            outb[pk[i].y] = label;
          }
        }
      }
    }

    // ---- dirty segment rescans from compact list ----
    if (ndRaw > DLCAP) {
      // overflow fallback: full rescan (correct regardless)
      for (int s = wid; s < NSEG; s += 16) {
        int i = (s << 6) + lane;
        unsigned long long k = 0ULL;
        if (i < V && ((s_uncl[i >> 5] >> (i & 31)) & 1u)) {
          int2 v = pk[i];
          k = ((unsigned long long)(unsigned)v.x << 32) | (unsigned)(~v.y);
        }
        for (int o = 32; o > 0; o >>= 1) {
          unsigned long long ok = __shfl_down(k, o);
          if (ok > k) k = ok;
        }
        if (lane == 0) s_segkey[s] = k;
      }
      for (int s = tid; s < CCAP / 64; s += 1024) s_dirty[s] = 0;
    } else {
      for (int d = wid; d < ndRaw; d += 16) {
        int s = s_dlist[d];
        if (lane == 0) s_dirty[s] = 0;
        int i = (s << 6) + lane;
        unsigned long long k = 0ULL;
        if (i < V && ((s_uncl[i >> 5] >> (i & 31)) & 1u)) {
          int2 v = pk[i];
          k = ((unsigned long long)(unsigned)v.x << 32) | (unsigned)(~v.y);
        }
        for (int o = 32; o > 0; o >>= 1) {
          unsigned long long ok = __shfl_down(k, o);
          if (ok > k) k = ok;
        }
        if (lane == 0) s_segkey[s] = k;
      }
    }
    __syncthreads();   // B2

    // ---- argmax over segment keys into next slot ----
    {
      unsigned long long k = 0ULL;
      for (int s = tid; s < NSEG; s += 1024) {
        unsigned long long v = s_segkey[s];
        if (v > k) k = v;
      }
      for (int o = 32; o > 0; o >>= 1) {
        unsigned long long ok = __shfl_down(k, o);
        if (ok > k) k = ok;
      }
      if (lane == 0) atomicMax(&s_bestkey[nxt], k);
    }
    __syncthreads();   // B3
    t++;
  }
}

// ---------------- launch ----------------

extern "C" void kernel_launch(void* const* d_in, const int* in_sizes, int n_in,
                              void* d_out, int out_size, void* d_ws, size_t ws_size,
                              hipStream_t stream) {
  const float* in = (const float*)d_in[0];
  int* out = (int*)d_out;

  size_t hist_bytes = (size_t)BATCH * NCELL * sizeof(int);
  size_t off_bytes  = (size_t)BATCH * (NCELL + 1) * sizeof(int);
  size_t cur_bytes  = (size_t)BATCH * NCELL * sizeof(int);
  size_t emb_bytes  = (size_t)BATCH * CCAP * sizeof(float2);
  size_t pk_bytes   = (size_t)BATCH * CCAP * sizeof(int2);

  size_t o_hist = 256;
  size_t o_off  = (o_hist + hist_bytes + 255) & ~(size_t)255;
  size_t o_cur  = (o_off + off_bytes + 255) & ~(size_t)255;
  size_t o_emb  = (o_cur + cur_bytes + 255) & ~(size_t)255;
  size_t o_pk   = (o_emb + emb_bytes + 255) & ~(size_t)255;
  size_t need   = o_pk + pk_bytes;

  if (ws_size < need) {
    fill_kernel<<<(out_size + 1023) / 1024, 1024, 0, stream>>>(out, 2000000, out_size);
    return;
  }

  int*    hist = (int*)((char*)d_ws + o_hist);
  int*    off  = (int*)((char*)d_ws + o_off);
  int*    cur  = (int*)((char*)d_ws + o_cur);
  float2* emb  = (float2*)((char*)d_ws + o_emb);
  int2*   pk   = (int2*)((char*)d_ws + o_pk);

  hipMemsetAsync(hist, 0, hist_bytes, stream);
  hist_kernel<<<(BATCH * NPIX) / 256, 256, 0, stream>>>(in, out, hist);
  scan_kernel<<<BATCH, 1024, 0, stream>>>(hist, off, cur);
  scatter_kernel<<<(BATCH * NPIX) / 256, 256, 0, stream>>>(in, cur, emb, pk);
  cluster_kernel<<<BATCH, 1024, 0, stream>>>(in, out, emb, pk, off);
}

// Round 7
// 1027.815 us; speedup vs baseline: 3.4406x; 1.0937x over previous
//
#include <hip/hip_runtime.h>
#include <math.h>

#define BATCH 4
#define HH 512
#define WW 1024
#define NPIX (HH*WW)          // 524288 = 2^19
#define CCAP 196608           // compaction capacity per image (expected ~161.7k valid)
#define GX 64
#define GY 48
#define NCELL (GX*GY)         // 3072 cells, 0.0625 x 0.0625 over [-1,3]x[-1,2]
#define CELL 0.0625f
#define INVCELL 16.0f
#define SEGSZ 256             // pixels per argmax-cache segment
#define NSEGMAX (CCAP/SEGSZ)  // 768
#define DLCAP 2048            // dirty-segment list capacity

// ---------------- XLA:CPU f32 math replicas (unchanged from passing rounds) ----
__device__ __forceinline__ float xla_tanhf(float x) {
  if (fabsf(x) < 0.0004f) return x;
  float xc = fminf(fmaxf(x, -7.90531110763549805f), 7.90531110763549805f);
  float x2 = __fmul_rn(xc, xc);
  float p = -2.76076847742355e-16f;
  p = fmaf(x2, p, 2.00018790482477e-13f);
  p = fmaf(x2, p, -8.60467152213735e-11f);
  p = fmaf(x2, p, 5.12229709037114e-08f);
  p = fmaf(x2, p, 1.48572235717979e-05f);
  p = fmaf(x2, p, 6.37261928875436e-04f);
  p = fmaf(x2, p, 4.89352455891786e-03f);
  p = __fmul_rn(xc, p);
  float q = fmaf(x2, 1.19825839466702e-06f, 1.18534705686654e-04f);
  q = fmaf(x2, q, 2.26843463243900e-03f);
  q = fmaf(x2, q, 4.89352518554385e-03f);
  return __fdiv_rn(p, q);
}

__device__ __forceinline__ float xla_expf(float x) {
  float xc = fminf(fmaxf(x, -87.3365478515625f), 88.72283935546875f);
  float m = floorf(fmaf(xc, 1.44269504088896341f, 0.5f));
  float r = fmaf(m, -0.693359375f, xc);
  r = fmaf(m, 2.12194440e-4f, r);
  float r2 = __fmul_rn(r, r);
  float p = 1.9875691500e-4f;
  p = fmaf(p, r, 1.3981999507e-3f);
  p = fmaf(p, r, 8.3334519073e-3f);
  p = fmaf(p, r, 4.1665795894e-2f);
  p = fmaf(p, r, 1.6666665459e-1f);
  p = fmaf(p, r, 5.0000001201e-1f);
  float y = fmaf(r2, p, r);
  y = __fadd_rn(y, 1.0f);
  return ldexpf(y, (int)m);
}

__device__ __forceinline__ float xla_sigmoidf(float x) {
  return fmaf(0.5f, xla_tanhf(__fmul_rn(0.5f, x)), 0.5f);
}

// Proposal test — byte-identical decision logic to the passing kernels.
__device__ __forceinline__ bool prop_test(float2 e, float cx, float cy,
                                          float den0, float den1,
                                          float inv0, float inv1) {
  float d0 = __fsub_rn(e.x, cx), d1 = __fsub_rn(e.y, cy);
  float dd0 = __fmul_rn(d0, d0), dd1 = __fmul_rn(d1, d1);
  float zf = fmaf(dd0, inv0, __fmul_rn(dd1, inv1));
  if (zf < 0.6921472f) return true;
  if (zf <= 0.6941472f) {
    float t0 = __fdiv_rn(dd0, den0);
    float t1 = __fdiv_rn(dd1, den1);
    float z = __fadd_rn(t0, t1);
    return xla_expf(-z) > 0.5f;
  }
  return false;
}

__device__ __forceinline__ int cell_of_x(float ex) {
  int c = (int)((ex + 1.0f) * INVCELL);
  return min(max(c, 0), GX - 1);
}
__device__ __forceinline__ int cell_of_y(float ey) {
  int c = (int)((ey + 1.0f) * INVCELL);
  return min(max(c, 0), GY - 1);
}

// ---------------- kernels ----------------

__global__ __launch_bounds__(1024) void fill_kernel(int* out, int val, int n) {
  int i = blockIdx.x * 1024 + threadIdx.x;
  if (i < n) out[i] = val;
}

__global__ __launch_bounds__(256) void hist_kernel(const float* __restrict__ in,
                                                   int* __restrict__ out,
                                                   int* __restrict__ hist) {
  int gid = blockIdx.x * 256 + threadIdx.x;
  int b = gid >> 19;
  int p = gid & (NPIX - 1);
  const float* base = in + (size_t)b * 5 * NPIX;
  float seed = base[(size_t)4 * NPIX + p];
  out[gid] = 0;
  if (seed > 0.5f) {
    float ox = base[p];
    float oy = base[(size_t)NPIX + p];
    int col = p & (WW - 1);
    int row = p >> 10;
    float gx = __fmul_rn((float)col, 2.0f / 1023.0f);
    float gy = __fmul_rn((float)row, 1.0f / 511.0f);
    float ex = __fadd_rn(xla_tanhf(ox), gx);
    float ey = __fadd_rn(xla_tanhf(oy), gy);
    atomicAdd(&hist[b * NCELL + cell_of_y(ey) * GX + cell_of_x(ex)], 1);
  }
}

__global__ __launch_bounds__(1024) void scan_kernel(const int* __restrict__ hist,
                                                    int* __restrict__ off,
                                                    int* __restrict__ cursor) {
  __shared__ int s_c[NCELL];
  __shared__ int s_ps[1024];
  int b = blockIdx.x, t = threadIdx.x;
  const int* h = hist + b * NCELL;
  for (int i = t; i < NCELL; i += 1024) s_c[i] = h[i];
  __syncthreads();
  int a = s_c[3 * t], b2 = s_c[3 * t + 1], c2 = s_c[3 * t + 2];
  int th = a + b2 + c2;
  s_ps[t] = th;
  __syncthreads();
  for (int d = 1; d < 1024; d <<= 1) {
    int v = (t >= d) ? s_ps[t - d] : 0;
    __syncthreads();
    s_ps[t] += v;
    __syncthreads();
  }
  int excl = s_ps[t] - th;
  int* ob = off + b * (NCELL + 1);
  int* cb = cursor + b * NCELL;
  ob[3 * t] = excl;              cb[3 * t] = excl;
  ob[3 * t + 1] = excl + a;      cb[3 * t + 1] = excl + a;
  ob[3 * t + 2] = excl + a + b2; cb[3 * t + 2] = excl + a + b2;
  if (t == 1023) ob[NCELL] = s_ps[1023];
}

__global__ __launch_bounds__(256) void scatter_kernel(const float* __restrict__ in,
                                                      int* __restrict__ cursor,
                                                      float2* __restrict__ emb,
                                                      int2* __restrict__ pk) {
  int gid = blockIdx.x * 256 + threadIdx.x;
  int b = gid >> 19;
  int p = gid & (NPIX - 1);
  const float* base = in + (size_t)b * 5 * NPIX;
  float seed = base[(size_t)4 * NPIX + p];
  if (seed > 0.5f) {
    float ox = base[p];
    float oy = base[(size_t)NPIX + p];
    int col = p & (WW - 1);
    int row = p >> 10;
    float gx = __fmul_rn((float)col, 2.0f / 1023.0f);
    float gy = __fmul_rn((float)row, 1.0f / 511.0f);
    float ex = __fadd_rn(xla_tanhf(ox), gx);
    float ey = __fadd_rn(xla_tanhf(oy), gy);
    float smv = xla_sigmoidf(seed);
    int cell = cell_of_y(ey) * GX + cell_of_x(ex);
    int slot = atomicAdd(&cursor[b * NCELL + cell], 1);
    if (slot < CCAP) {
      emb[(size_t)b * CCAP + slot] = make_float2(ex, ey);
      pk[(size_t)b * CCAP + slot]  = make_int2(__float_as_int(smv), p);
    }
  }
}

// Segment scan helper: computes (key, ci) over one 256-px segment and, if a
// winner exists, the winner lane writes key/ci and aux=(cx,cy,den0,den1).
// checkAlive=false only for the initial build (all pixels alive).
__device__ __forceinline__ void seg_rescan(int s, int V, int lane,
    const unsigned* s_uncl, const int2* __restrict__ pk,
    const float2* __restrict__ emb, const float* __restrict__ base,
    unsigned long long* s_segkey, int* s_segci, float4* s_segaux,
    bool checkAlive) {
  unsigned long long bk = 0ULL; int bci = -1; int bpx = 0;
  #pragma unroll
  for (int j = 0; j < 4; ++j) {
    int i = (s << 8) + (j << 6) + lane;
    if (i < V) {
      bool alive = !checkAlive || ((s_uncl[i >> 5] >> (i & 31)) & 1u);
      if (alive) {
        int2 v = pk[i];
        unsigned long long k = ((unsigned long long)(unsigned)v.x << 32) | (unsigned)(~v.y);
        if (k > bk) { bk = k; bci = i; bpx = v.y; }
      }
    }
  }
  unsigned long long mk = bk; int mci = bci;
  #pragma unroll
  for (int o = 1; o < 64; o <<= 1) {
    unsigned long long ok = __shfl_xor(mk, o);
    int oci = __shfl_xor(mci, o);
    if (ok > mk) { mk = ok; mci = oci; }
  }
  if (lane == 0) { s_segkey[s] = mk; s_segci[s] = mci; }
  if (mk != 0ULL && bk == mk) {          // unique winner lane
    float2 e = emb[mci];
    float sxv = base[(size_t)2 * NPIX + bpx];
    float syv = base[(size_t)3 * NPIX + bpx];
    float d0 = __fmul_rn(2.0f, __fmul_rn(sxv, sxv));   // ref: 2.0 * s**2
    float d1 = __fmul_rn(2.0f, __fmul_rn(syv, syv));
    s_segaux[s] = make_float4(e.x, e.y, d0, d1);
  }
}

// One workgroup per image. 2 barriers/iteration:
//   [wave-redundant argmax from seg caches -> aux (LDS) -> pass1] -> B1 ->
//   [labels if accept + winner-removed segment rescans + resets] -> B2
__global__ __launch_bounds__(1024) void cluster_kernel(const float* __restrict__ in,
                                                       int* __restrict__ out,
                                                       const float2* __restrict__ emb_all,
                                                       const int2* __restrict__ pk_all,
                                                       const int* __restrict__ off_g) {
  __shared__ unsigned int s_uncl[CCAP / 32];            // 24 KB
  __shared__ int s_off[NCELL + 1];                      // 12 KB
  __shared__ unsigned long long s_segkey[NSEGMAX];      // 6 KB
  __shared__ int s_segci[NSEGMAX];                      // 3 KB
  __shared__ float4 s_segaux[NSEGMAX];                  // 12 KB
  __shared__ int s_dlist[DLCAP];                        // 8 KB
  __shared__ int s_pc[2];
  __shared__ int s_uc[2];
  __shared__ int s_nd[2];

  int b = blockIdx.x;
  int tid = threadIdx.x;
  int lane = tid & 63;
  int wid = tid >> 6;
  const int* offb = off_g + b * (NCELL + 1);
  int V = offb[NCELL];
  const float2* emb = emb_all + (size_t)b * CCAP;
  const int2*   pk  = pk_all  + (size_t)b * CCAP;
  int* outb = out + (size_t)b * NPIX;
  const float* base = in + (size_t)b * 5 * NPIX;

  if (V > CCAP) {   // capacity overflow marker
    for (int i = tid; i < NPIX; i += 1024) outb[i] = 1000000;
    return;
  }
  int NSEG = (V + SEGSZ - 1) >> 8;

  for (int i = tid; i <= NCELL; i += 1024) s_off[i] = offb[i];
  for (int w = tid; w < CCAP / 32; w += 1024) {
    int basebit = w << 5;
    unsigned m;
    if (basebit + 32 <= V)      m = 0xffffffffu;
    else if (basebit >= V)      m = 0u;
    else                        m = (1u << (V - basebit)) - 1u;
    s_uncl[w] = m;
  }
  if (tid < 2) { s_pc[tid] = 0; s_uc[tid] = 0; s_nd[tid] = 0; }
  __syncthreads();

  // build segment caches (all pixels alive)
  for (int s = wid; s < NSEG; s += 16)
    seg_rescan(s, V, lane, s_uncl, pk, emb, base, s_segkey, s_segci, s_segaux, false);
  __syncthreads();

  int ucount = V, count = 1, guard = 0;
  int t = 0;
  while (ucount > 64 && guard++ <= CCAP) {
    int cur = t & 1, nxt = cur ^ 1;

    // ---- wave-redundant argmax over segment keys (no barrier, no atomics) ----
    unsigned long long key = 0ULL; int sg = -1;
    for (int s = lane; s < NSEG; s += 64) {
      unsigned long long v = s_segkey[s];
      if (v > key) { key = v; sg = s; }
    }
    #pragma unroll
    for (int o = 1; o < 64; o <<= 1) {
      unsigned long long ok = __shfl_xor(key, o);
      int osg = __shfl_xor(sg, o);
      if (ok > key) { key = ok; sg = osg; }
    }
    if (key == 0ULL) break;
    float sm = __uint_as_float((unsigned)(key >> 32));
    if (sm < 0.5f) break;              // ref's new_done (provably never fires)

    float4 aux = s_segaux[sg];         // broadcast LDS read
    float cx = aux.x, cy = aux.y, den0 = aux.z, den1 = aux.w;
    float inv0 = 1.0f / den0;
    float inv1 = 1.0f / den1;
    float ry = sqrtf(__fmul_rn(den1, 0.6971472f)) * 1.00001f;
    int r0 = cell_of_y(cy - ry);
    int r1 = cell_of_y(cy + ry);
    int nr = r1 - r0 + 1;
    int pairid = wid >> 1;

    // ---- pass 1: proposal + count + removal + winner-removed dirty list ----
    int pc = 0, uc = 0;
    for (int rr = pairid; rr < nr; rr += 8) {
      int r = r0 + rr;
      float ylo = fmaf((float)r, CELL, -1.0f);
      float dy = fmaxf(0.0f, fmaxf(ylo - cy, cy - (ylo + CELL))) * 0.999999f;
      float rem = 0.6971472f - dy * dy * inv1;
      if (rem <= 0.0f) continue;
      float dxm = sqrtf(den0 * rem) * 1.00001f;
      int c0 = cell_of_x(cx - dxm), c1 = cell_of_x(cx + dxm);
      int rs = s_off[r * GX + c0], re = s_off[r * GX + c1 + 1];
      for (int i0 = rs + ((wid & 1) << 7); i0 < re; i0 += 256) {
        int i = i0 + lane;
        int i2 = i + 64;
        bool p0 = (i < re) && prop_test(emb[i], cx, cy, den0, den1, inv0, inv1);
        bool p1 = (i2 < re) && prop_test(emb[i2], cx, cy, den0, den1, inv0, inv1);
        unsigned long long m0 = __ballot(p0);
        unsigned long long m1 = __ballot(p1);
        if ((m0 | m1) == 0ULL) continue;
        int off = i0 & 31;
        unsigned w = (unsigned)(i0 >> 5);
        unsigned bits = 0; unsigned tw = w;
        if (lane == 0)      { pc += (int)__popcll(m0); bits = (unsigned)(m0 << off); tw = w; }
        else if (lane == 1) { bits = (unsigned)(m0 >> (32 - off)); tw = w + 1; }
        else if (lane == 2) { if (off > 0) bits = (unsigned)(m0 >> (64 - off)); tw = w + 2; }
        else if (lane == 3) { pc += (int)__popcll(m1); bits = (unsigned)(m1 << off); tw = w + 2; }
        else if (lane == 4) { bits = (unsigned)(m1 >> (32 - off)); tw = w + 3; }
        else if (lane == 5) { if (off > 0) bits = (unsigned)(m1 >> (64 - off)); tw = w + 4; }
        if (bits) {
          unsigned old = atomicAnd(&s_uncl[tw], ~bits);
          unsigned remv = old & bits;
          if (remv) {
            uc += __popc(remv);
            int seg = (int)(tw >> 3);           // 256 px = 8 words
            int ciw = s_segci[seg];
            if ((ciw >> 5) == (int)tw && ((remv >> (ciw & 31)) & 1u)) {
              int pos = atomicAdd(&s_nd[cur], 1);
              if (pos < DLCAP) s_dlist[pos] = seg;
            }
          }
        }
      }
    }
    for (int o = 32; o > 0; o >>= 1) {
      pc += __shfl_down(pc, o);
      uc += __shfl_down(uc, o);
    }
    if (lane == 0 && (pc | uc)) {
      if (pc) atomicAdd(&s_pc[cur], pc);
      if (uc) atomicAdd(&s_uc[cur], uc);
    }
    __syncthreads();   // B1

    int pcT = s_pc[cur];
    int ucR = s_uc[cur];            // total removed this iter (includes seed)
    int ndRaw = s_nd[cur];
    bool accept = (pcT > 64) && (2 * (ucR - 1) > pcT);  // ref uc excludes seed
    int label = count & 255;
    if (accept) count++;
    ucount -= ucR;
    if (tid == 0) { s_pc[nxt] = 0; s_uc[nxt] = 0; s_nd[nxt] = 0; }

    // ---- labels (rare: only accepted iterations) ----
    if (accept) {
      for (int rr = pairid; rr < nr; rr += 8) {
        int r = r0 + rr;
        float ylo = fmaf((float)r, CELL, -1.0f);
        float dy = fmaxf(0.0f, fmaxf(ylo - cy, cy - (ylo + CELL))) * 0.999999f;
        float rem = 0.6971472f - dy * dy * inv1;
        if (rem <= 0.0f) continue;
        float dxm = sqrtf(den0 * rem) * 1.00001f;
        int c0 = cell_of_x(cx - dxm), c1 = cell_of_x(cx + dxm);
        int rs = s_off[r * GX + c0], re = s_off[r * GX + c1 + 1];
        for (int i = rs + ((wid & 1) << 6) + lane; i < re; i += 128) {
          if (prop_test(emb[i], cx, cy, den0, den1, inv0, inv1)) {
            outb[pk[i].y] = label;
          }
        }
      }
    }

    // ---- rescans: only segments whose cached winner was removed ----
    if (ndRaw > DLCAP) {
      for (int s = wid; s < NSEG; s += 16)
        seg_rescan(s, V, lane, s_uncl, pk, emb, base, s_segkey, s_segci, s_segaux, true);
    } else {
      for (int d = wid; d < ndRaw; d += 16)
        seg_rescan(s_dlist[d], V, lane, s_uncl, pk, emb, base, s_segkey, s_segci, s_segaux, true);
    }
    __syncthreads();   // B2
    t++;
  }
}

// ---------------- launch ----------------

extern "C" void kernel_launch(void* const* d_in, const int* in_sizes, int n_in,
                              void* d_out, int out_size, void* d_ws, size_t ws_size,
                              hipStream_t stream) {
  const float* in = (const float*)d_in[0];
  int* out = (int*)d_out;

  size_t hist_bytes = (size_t)BATCH * NCELL * sizeof(int);
  size_t off_bytes  = (size_t)BATCH * (NCELL + 1) * sizeof(int);
  size_t cur_bytes  = (size_t)BATCH * NCELL * sizeof(int);
  size_t emb_bytes  = (size_t)BATCH * CCAP * sizeof(float2);
  size_t pk_bytes   = (size_t)BATCH * CCAP * sizeof(int2);

  size_t o_hist = 256;
  size_t o_off  = (o_hist + hist_bytes + 255) & ~(size_t)255;
  size_t o_cur  = (o_off + off_bytes + 255) & ~(size_t)255;
  size_t o_emb  = (o_cur + cur_bytes + 255) & ~(size_t)255;
  size_t o_pk   = (o_emb + emb_bytes + 255) & ~(size_t)255;
  size_t need   = o_pk + pk_bytes;

  if (ws_size < need) {
    fill_kernel<<<(out_size + 1023) / 1024, 1024, 0, stream>>>(out, 2000000, out_size);
    return;
  }

  int*    hist = (int*)((char*)d_ws + o_hist);
  int*    off  = (int*)((char*)d_ws + o_off);
  int*    cur  = (int*)((char*)d_ws + o_cur);
  float2* emb  = (float2*)((char*)d_ws + o_emb);
  int2*   pk   = (int2*)((char*)d_ws + o_pk);

  hipMemsetAsync(hist, 0, hist_bytes, stream);
  hist_kernel<<<(BATCH * NPIX) / 256, 256, 0, stream>>>(in, out, hist);
  scan_kernel<<<BATCH, 1024, 0, stream>>>(hist, off, cur);
  scatter_kernel<<<(BATCH * NPIX) / 256, 256, 0, stream>>>(in, cur, emb, pk);
  cluster_kernel<<<BATCH, 1024, 0, stream>>>(in, out, emb, pk, off);
}

// Round 8
// 1023.652 us; speedup vs baseline: 3.4546x; 1.0041x over previous
//
#include <hip/hip_runtime.h>
#include <math.h>

#define BATCH 4
#define HH 512
#define WW 1024
#define NPIX (HH*WW)          // 524288 = 2^19
#define CCAP 196608           // compaction capacity per image (expected ~161.7k valid)
#define GX 64
#define GY 48
#define NCELL (GX*GY)         // 3072 cells, 0.0625 x 0.0625 over [-1,3]x[-1,2]
#define CELL 0.0625f
#define INVCELL 16.0f
#define SEGSZ 256             // pixels per argmax-cache segment
#define NSEGMAX (CCAP/SEGSZ)  // 768
#define DLCAP 2048            // dirty-segment list capacity

// ---------------- XLA:CPU f32 math replicas (unchanged from passing rounds) ----
__device__ __forceinline__ float xla_tanhf(float x) {
  if (fabsf(x) < 0.0004f) return x;
  float xc = fminf(fmaxf(x, -7.90531110763549805f), 7.90531110763549805f);
  float x2 = __fmul_rn(xc, xc);
  float p = -2.76076847742355e-16f;
  p = fmaf(x2, p, 2.00018790482477e-13f);
  p = fmaf(x2, p, -8.60467152213735e-11f);
  p = fmaf(x2, p, 5.12229709037114e-08f);
  p = fmaf(x2, p, 1.48572235717979e-05f);
  p = fmaf(x2, p, 6.37261928875436e-04f);
  p = fmaf(x2, p, 4.89352455891786e-03f);
  p = __fmul_rn(xc, p);
  float q = fmaf(x2, 1.19825839466702e-06f, 1.18534705686654e-04f);
  q = fmaf(x2, q, 2.26843463243900e-03f);
  q = fmaf(x2, q, 4.89352518554385e-03f);
  return __fdiv_rn(p, q);
}

__device__ __forceinline__ float xla_expf(float x) {
  float xc = fminf(fmaxf(x, -87.3365478515625f), 88.72283935546875f);
  float m = floorf(fmaf(xc, 1.44269504088896341f, 0.5f));
  float r = fmaf(m, -0.693359375f, xc);
  r = fmaf(m, 2.12194440e-4f, r);
  float r2 = __fmul_rn(r, r);
  float p = 1.9875691500e-4f;
  p = fmaf(p, r, 1.3981999507e-3f);
  p = fmaf(p, r, 8.3334519073e-3f);
  p = fmaf(p, r, 4.1665795894e-2f);
  p = fmaf(p, r, 1.6666665459e-1f);
  p = fmaf(p, r, 5.0000001201e-1f);
  float y = fmaf(r2, p, r);
  y = __fadd_rn(y, 1.0f);
  return ldexpf(y, (int)m);
}

__device__ __forceinline__ float xla_sigmoidf(float x) {
  return fmaf(0.5f, xla_tanhf(__fmul_rn(0.5f, x)), 0.5f);
}

// Proposal test — byte-identical decision logic to the passing kernels.
__device__ __forceinline__ bool prop_test(float2 e, float cx, float cy,
                                          float den0, float den1,
                                          float inv0, float inv1) {
  float d0 = __fsub_rn(e.x, cx), d1 = __fsub_rn(e.y, cy);
  float dd0 = __fmul_rn(d0, d0), dd1 = __fmul_rn(d1, d1);
  float zf = fmaf(dd0, inv0, __fmul_rn(dd1, inv1));
  if (zf < 0.6921472f) return true;
  if (zf <= 0.6941472f) {
    float t0 = __fdiv_rn(dd0, den0);
    float t1 = __fdiv_rn(dd1, den1);
    float z = __fadd_rn(t0, t1);
    return xla_expf(-z) > 0.5f;
  }
  return false;
}

__device__ __forceinline__ int cell_of_x(float ex) {
  int c = (int)((ex + 1.0f) * INVCELL);
  return min(max(c, 0), GX - 1);
}
__device__ __forceinline__ int cell_of_y(float ey) {
  int c = (int)((ey + 1.0f) * INVCELL);
  return min(max(c, 0), GY - 1);
}

// ---------------- kernels ----------------

__global__ __launch_bounds__(1024) void fill_kernel(int* out, int val, int n) {
  int i = blockIdx.x * 1024 + threadIdx.x;
  if (i < n) out[i] = val;
}

__global__ __launch_bounds__(256) void hist_kernel(const float* __restrict__ in,
                                                   int* __restrict__ out,
                                                   int* __restrict__ hist) {
  int gid = blockIdx.x * 256 + threadIdx.x;
  int b = gid >> 19;
  int p = gid & (NPIX - 1);
  const float* base = in + (size_t)b * 5 * NPIX;
  float seed = base[(size_t)4 * NPIX + p];
  out[gid] = 0;
  if (seed > 0.5f) {
    float ox = base[p];
    float oy = base[(size_t)NPIX + p];
    int col = p & (WW - 1);
    int row = p >> 10;
    float gx = __fmul_rn((float)col, 2.0f / 1023.0f);
    float gy = __fmul_rn((float)row, 1.0f / 511.0f);
    float ex = __fadd_rn(xla_tanhf(ox), gx);
    float ey = __fadd_rn(xla_tanhf(oy), gy);
    atomicAdd(&hist[b * NCELL + cell_of_y(ey) * GX + cell_of_x(ex)], 1);
  }
}

__global__ __launch_bounds__(1024) void scan_kernel(const int* __restrict__ hist,
                                                    int* __restrict__ off,
                                                    int* __restrict__ cursor) {
  __shared__ int s_c[NCELL];
  __shared__ int s_ps[1024];
  int b = blockIdx.x, t = threadIdx.x;
  const int* h = hist + b * NCELL;
  for (int i = t; i < NCELL; i += 1024) s_c[i] = h[i];
  __syncthreads();
  int a = s_c[3 * t], b2 = s_c[3 * t + 1], c2 = s_c[3 * t + 2];
  int th = a + b2 + c2;
  s_ps[t] = th;
  __syncthreads();
  for (int d = 1; d < 1024; d <<= 1) {
    int v = (t >= d) ? s_ps[t - d] : 0;
    __syncthreads();
    s_ps[t] += v;
    __syncthreads();
  }
  int excl = s_ps[t] - th;
  int* ob = off + b * (NCELL + 1);
  int* cb = cursor + b * NCELL;
  ob[3 * t] = excl;              cb[3 * t] = excl;
  ob[3 * t + 1] = excl + a;      cb[3 * t + 1] = excl + a;
  ob[3 * t + 2] = excl + a + b2; cb[3 * t + 2] = excl + a + b2;
  if (t == 1023) ob[NCELL] = s_ps[1023];
}

__global__ __launch_bounds__(256) void scatter_kernel(const float* __restrict__ in,
                                                      int* __restrict__ cursor,
                                                      float2* __restrict__ emb,
                                                      int2* __restrict__ pk) {
  int gid = blockIdx.x * 256 + threadIdx.x;
  int b = gid >> 19;
  int p = gid & (NPIX - 1);
  const float* base = in + (size_t)b * 5 * NPIX;
  float seed = base[(size_t)4 * NPIX + p];
  if (seed > 0.5f) {
    float ox = base[p];
    float oy = base[(size_t)NPIX + p];
    int col = p & (WW - 1);
    int row = p >> 10;
    float gx = __fmul_rn((float)col, 2.0f / 1023.0f);
    float gy = __fmul_rn((float)row, 1.0f / 511.0f);
    float ex = __fadd_rn(xla_tanhf(ox), gx);
    float ey = __fadd_rn(xla_tanhf(oy), gy);
    float smv = xla_sigmoidf(seed);
    int cell = cell_of_y(ey) * GX + cell_of_x(ex);
    int slot = atomicAdd(&cursor[b * NCELL + cell], 1);
    if (slot < CCAP) {
      emb[(size_t)b * CCAP + slot] = make_float2(ex, ey);
      pk[(size_t)b * CCAP + slot]  = make_int2(__float_as_int(smv), p);
    }
  }
}

// Segment scan helper (unchanged from passing round 7).
__device__ __forceinline__ void seg_rescan(int s, int V, int lane,
    const unsigned* s_uncl, const int2* __restrict__ pk,
    const float2* __restrict__ emb, const float* __restrict__ base,
    unsigned long long* s_segkey, int* s_segci, float4* s_segaux,
    bool checkAlive) {
  unsigned long long bk = 0ULL; int bci = -1; int bpx = 0;
  #pragma unroll
  for (int j = 0; j < 4; ++j) {
    int i = (s << 8) + (j << 6) + lane;
    if (i < V) {
      bool alive = !checkAlive || ((s_uncl[i >> 5] >> (i & 31)) & 1u);
      if (alive) {
        int2 v = pk[i];
        unsigned long long k = ((unsigned long long)(unsigned)v.x << 32) | (unsigned)(~v.y);
        if (k > bk) { bk = k; bci = i; bpx = v.y; }
      }
    }
  }
  unsigned long long mk = bk; int mci = bci;
  #pragma unroll
  for (int o = 1; o < 64; o <<= 1) {
    unsigned long long ok = __shfl_xor(mk, o);
    int oci = __shfl_xor(mci, o);
    if (ok > mk) { mk = ok; mci = oci; }
  }
  if (lane == 0) { s_segkey[s] = mk; s_segci[s] = mci; }
  if (mk != 0ULL && bk == mk) {          // unique winner lane
    float2 e = emb[mci];
    float sxv = base[(size_t)2 * NPIX + bpx];
    float syv = base[(size_t)3 * NPIX + bpx];
    float d0 = __fmul_rn(2.0f, __fmul_rn(sxv, sxv));   // ref: 2.0 * s**2
    float d1 = __fmul_rn(2.0f, __fmul_rn(syv, syv));
    s_segaux[s] = make_float4(e.x, e.y, d0, d1);
  }
}

// Boundary range: per-pixel prop_test, ballot-aggregated clears (r7 logic).
__device__ __forceinline__ void bnd_clear(int lo, int hi, int wid, int lane,
    const float2* __restrict__ emb, float cx, float cy, float den0, float den1,
    float inv0, float inv1, unsigned* s_uncl, const int* s_segci,
    int* s_dlist, int* s_nd_cur, int &pc, int &uc) {
  for (int i0 = lo + ((wid & 1) << 7); i0 < hi; i0 += 256) {
    int i = i0 + lane;
    int i2 = i + 64;
    bool p0 = (i < hi) && prop_test(emb[i], cx, cy, den0, den1, inv0, inv1);
    bool p1 = (i2 < hi) && prop_test(emb[i2], cx, cy, den0, den1, inv0, inv1);
    unsigned long long m0 = __ballot(p0);
    unsigned long long m1 = __ballot(p1);
    if ((m0 | m1) == 0ULL) continue;
    int off = i0 & 31;
    unsigned w = (unsigned)(i0 >> 5);
    unsigned bits = 0; unsigned tw = w;
    if (lane == 0)      { pc += (int)__popcll(m0); bits = (unsigned)(m0 << off); tw = w; }
    else if (lane == 1) { bits = (unsigned)(m0 >> (32 - off)); tw = w + 1; }
    else if (lane == 2) { if (off > 0) bits = (unsigned)(m0 >> (64 - off)); tw = w + 2; }
    else if (lane == 3) { pc += (int)__popcll(m1); bits = (unsigned)(m1 << off); tw = w + 2; }
    else if (lane == 4) { bits = (unsigned)(m1 >> (32 - off)); tw = w + 3; }
    else if (lane == 5) { if (off > 0) bits = (unsigned)(m1 >> (64 - off)); tw = w + 4; }
    if (bits) {
      unsigned old = atomicAnd(&s_uncl[tw], ~bits);
      unsigned remv = old & bits;
      if (remv) {
        uc += __popc(remv);
        int seg = (int)(tw >> 3);           // 256 px = 8 words
        int ciw = s_segci[seg];
        if ((ciw >> 5) == (int)tw && ((remv >> (ciw & 31)) & 1u)) {
          int pos = atomicAdd(s_nd_cur, 1);
          if (pos < DLCAP) s_dlist[pos] = seg;
        }
      }
    }
  }
}

// Interior range (certified all-proposed): pure word ops — no loads, no tests.
__device__ __forceinline__ void int_clear(int lo, int hi, int wid, int lane,
    unsigned* s_uncl, const int* s_segci, int* s_dlist, int* s_nd_cur,
    int &pc, int &uc) {
  if (lo >= hi) return;
  int wlo = lo >> 5, whi = (hi - 1) >> 5;
  for (int w = wlo + (wid & 1) + (lane << 1); w <= whi; w += 128) {
    unsigned m = 0xffffffffu;
    if (w == wlo) m &= (0xffffffffu << (lo & 31));
    if (w == whi) { int tpx = hi - (whi << 5); if (tpx < 32) m &= ((1u << tpx) - 1u); }
    pc += __popc(m);
    unsigned old = atomicAnd(&s_uncl[w], ~m);
    unsigned remv = old & m;
    if (remv) {
      uc += __popc(remv);
      int seg = w >> 3;
      int ciw = s_segci[seg];
      if ((ciw >> 5) == w && ((remv >> (ciw & 31)) & 1u)) {
        int pos = atomicAdd(s_nd_cur, 1);
        if (pos < DLCAP) s_dlist[pos] = seg;
      }
    }
  }
}

// One workgroup per image. 2 barriers/iteration (structure = passing round 7;
// pass-1 rows now split boundary/interior, interior = certified word ops).
__global__ __launch_bounds__(1024) void cluster_kernel(const float* __restrict__ in,
                                                       int* __restrict__ out,
                                                       const float2* __restrict__ emb_all,
                                                       const int2* __restrict__ pk_all,
                                                       const int* __restrict__ off_g) {
  __shared__ unsigned int s_uncl[CCAP / 32];            // 24 KB
  __shared__ int s_off[NCELL + 1];                      // 12 KB
  __shared__ unsigned long long s_segkey[NSEGMAX];      // 6 KB
  __shared__ int s_segci[NSEGMAX];                      // 3 KB
  __shared__ float4 s_segaux[NSEGMAX];                  // 12 KB
  __shared__ int s_dlist[DLCAP];                        // 8 KB
  __shared__ int s_pc[2];
  __shared__ int s_uc[2];
  __shared__ int s_nd[2];

  int b = blockIdx.x;
  int tid = threadIdx.x;
  int lane = tid & 63;
  int wid = tid >> 6;
  const int* offb = off_g + b * (NCELL + 1);
  int V = offb[NCELL];
  const float2* emb = emb_all + (size_t)b * CCAP;
  const int2*   pk  = pk_all  + (size_t)b * CCAP;
  int* outb = out + (size_t)b * NPIX;
  const float* base = in + (size_t)b * 5 * NPIX;

  if (V > CCAP) {   // capacity overflow marker
    for (int i = tid; i < NPIX; i += 1024) outb[i] = 1000000;
    return;
  }
  int NSEG = (V + SEGSZ - 1) >> 8;

  for (int i = tid; i <= NCELL; i += 1024) s_off[i] = offb[i];
  for (int w = tid; w < CCAP / 32; w += 1024) {
    int basebit = w << 5;
    unsigned m;
    if (basebit + 32 <= V)      m = 0xffffffffu;
    else if (basebit >= V)      m = 0u;
    else                        m = (1u << (V - basebit)) - 1u;
    s_uncl[w] = m;
  }
  if (tid < 2) { s_pc[tid] = 0; s_uc[tid] = 0; s_nd[tid] = 0; }
  __syncthreads();

  // build segment caches (all pixels alive)
  for (int s = wid; s < NSEG; s += 16)
    seg_rescan(s, V, lane, s_uncl, pk, emb, base, s_segkey, s_segci, s_segaux, false);
  __syncthreads();

  int ucount = V, count = 1, guard = 0;
  int t = 0;
  while (ucount > 64 && guard++ <= CCAP) {
    int cur = t & 1, nxt = cur ^ 1;

    // ---- wave-redundant argmax over segment keys (no barrier, no atomics) ----
    unsigned long long key = 0ULL; int sg = -1;
    for (int s = lane; s < NSEG; s += 64) {
      unsigned long long v = s_segkey[s];
      if (v > key) { key = v; sg = s; }
    }
    #pragma unroll
    for (int o = 1; o < 64; o <<= 1) {
      unsigned long long ok = __shfl_xor(key, o);
      int osg = __shfl_xor(sg, o);
      if (ok > key) { key = ok; sg = osg; }
    }
    if (key == 0ULL) break;
    float sm = __uint_as_float((unsigned)(key >> 32));
    if (sm < 0.5f) break;              // ref's new_done (provably never fires)

    float4 aux = s_segaux[sg];         // broadcast LDS read
    float cx = aux.x, cy = aux.y, den0 = aux.z, den1 = aux.w;
    float inv0 = 1.0f / den0;
    float inv1 = 1.0f / den1;
    float ry = sqrtf(__fmul_rn(den1, 0.6971472f)) * 1.00001f;
    int r0 = cell_of_y(cy - ry);
    int r1 = cell_of_y(cy + ry);
    int nr = r1 - r0 + 1;
    int pairid = wid >> 1;

    // ---- pass 1: boundary per-pixel + certified interior word ops ----
    int pc = 0, uc = 0;
    for (int rr = pairid; rr < nr; rr += 8) {
      int r = r0 + rr;
      float ylo = fmaf((float)r, CELL, -1.0f);
      float dy = fmaxf(0.0f, fmaxf(ylo - cy, cy - (ylo + CELL))) * 0.999999f;
      float rem = 0.6971472f - dy * dy * inv1;
      if (rem <= 0.0f) continue;
      float dxm = sqrtf(den0 * rem) * 1.00001f;
      int c0 = cell_of_x(cx - dxm), c1 = cell_of_x(cx + dxm);
      int rbase = r * GX;
      int rs = s_off[rbase + c0], re = s_off[rbase + c1 + 1];
      // certified interior col run [a,bb]: all 4 corners z < 0.6920 (proven r5 logic)
      int m0 = rs, m1 = rs;
      float dyc = fmaxf(fabsf(ylo - cy), fabsf(ylo + CELL - cy)) + 1e-5f;
      float remI = 0.6920f - dyc * dyc * inv1;
      if (remI > 0.0f) {
        float dxin = sqrtf(den0 * remI) * 0.9999f;
        int a  = (int)ceilf(fmaf(cx - dxin, INVCELL, INVCELL) + 1e-3f);
        int bb = (int)floorf(fmaf(cx + dxin, INVCELL, INVCELL) - 1e-3f) - 1;
        a = max(a, c0); bb = min(bb, c1);
        if (a <= bb) { m0 = s_off[rbase + a]; m1 = s_off[rbase + bb + 1]; }
      }
      bnd_clear(rs, m0, wid, lane, emb, cx, cy, den0, den1, inv0, inv1,
                s_uncl, s_segci, s_dlist, &s_nd[cur], pc, uc);
      int_clear(m0, m1, wid, lane, s_uncl, s_segci, s_dlist, &s_nd[cur], pc, uc);
      bnd_clear(m1, re, wid, lane, emb, cx, cy, den0, den1, inv0, inv1,
                s_uncl, s_segci, s_dlist, &s_nd[cur], pc, uc);
    }
    for (int o = 32; o > 0; o >>= 1) {
      pc += __shfl_down(pc, o);
      uc += __shfl_down(uc, o);
    }
    if (lane == 0 && (pc | uc)) {
      if (pc) atomicAdd(&s_pc[cur], pc);
      if (uc) atomicAdd(&s_uc[cur], uc);
    }
    __syncthreads();   // B1

    int pcT = s_pc[cur];
    int ucR = s_uc[cur];            // total removed this iter (includes seed)
    int ndRaw = s_nd[cur];
    bool accept = (pcT > 64) && (2 * (ucR - 1) > pcT);  // ref uc excludes seed
    int label = count & 255;
    if (accept) count++;
    ucount -= ucR;
    if (tid == 0) { s_pc[nxt] = 0; s_uc[nxt] = 0; s_nd[nxt] = 0; }

    // ---- labels (rare: only accepted iterations) ----
    if (accept) {
      for (int rr = pairid; rr < nr; rr += 8) {
        int r = r0 + rr;
        float ylo = fmaf((float)r, CELL, -1.0f);
        float dy = fmaxf(0.0f, fmaxf(ylo - cy, cy - (ylo + CELL))) * 0.999999f;
        float rem = 0.6971472f - dy * dy * inv1;
        if (rem <= 0.0f) continue;
        float dxm = sqrtf(den0 * rem) * 1.00001f;
        int c0 = cell_of_x(cx - dxm), c1 = cell_of_x(cx + dxm);
        int rbase = r * GX;
        int rs = s_off[rbase + c0], re = s_off[rbase + c1 + 1];
        int m0 = rs, m1 = rs;
        float dyc = fmaxf(fabsf(ylo - cy), fabsf(ylo + CELL - cy)) + 1e-5f;
        float remI = 0.6920f - dyc * dyc * inv1;
        if (remI > 0.0f) {
          float dxin = sqrtf(den0 * remI) * 0.9999f;
          int a  = (int)ceilf(fmaf(cx - dxin, INVCELL, INVCELL) + 1e-3f);
          int bb = (int)floorf(fmaf(cx + dxin, INVCELL, INVCELL) - 1e-3f) - 1;
          a = max(a, c0); bb = min(bb, c1);
          if (a <= bb) { m0 = s_off[rbase + a]; m1 = s_off[rbase + bb + 1]; }
        }
        int half = (wid & 1) << 6;
        for (int i = rs + half + lane; i < m0; i += 128)
          if (prop_test(emb[i], cx, cy, den0, den1, inv0, inv1)) outb[pk[i].y] = label;
        for (int i = m0 + half + lane; i < m1; i += 128)
          outb[pk[i].y] = label;
        for (int i = m1 + half + lane; i < re; i += 128)
          if (prop_test(emb[i], cx, cy, den0, den1, inv0, inv1)) outb[pk[i].y] = label;
      }
    }

    // ---- rescans: only segments whose cached winner was removed ----
    if (ndRaw > DLCAP) {
      for (int s = wid; s < NSEG; s += 16)
        seg_rescan(s, V, lane, s_uncl, pk, emb, base, s_segkey, s_segci, s_segaux, true);
    } else {
      for (int d = wid; d < ndRaw; d += 16)
        seg_rescan(s_dlist[d], V, lane, s_uncl, pk, emb, base, s_segkey, s_segci, s_segaux, true);
    }
    __syncthreads();   // B2
    t++;
  }
}

// ---------------- launch ----------------

extern "C" void kernel_launch(void* const* d_in, const int* in_sizes, int n_in,
                              void* d_out, int out_size, void* d_ws, size_t ws_size,
                              hipStream_t stream) {
  const float* in = (const float*)d_in[0];
  int* out = (int*)d_out;

  size_t hist_bytes = (size_t)BATCH * NCELL * sizeof(int);
  size_t off_bytes  = (size_t)BATCH * (NCELL + 1) * sizeof(int);
  size_t cur_bytes  = (size_t)BATCH * NCELL * sizeof(int);
  size_t emb_bytes  = (size_t)BATCH * CCAP * sizeof(float2);
  size_t pk_bytes   = (size_t)BATCH * CCAP * sizeof(int2);

  size_t o_hist = 256;
  size_t o_off  = (o_hist + hist_bytes + 255) & ~(size_t)255;
  size_t o_cur  = (o_off + off_bytes + 255) & ~(size_t)255;
  size_t o_emb  = (o_cur + cur_bytes + 255) & ~(size_t)255;
  size_t o_pk   = (o_emb + emb_bytes + 255) & ~(size_t)255;
  size_t need   = o_pk + pk_bytes;

  if (ws_size < need) {
    fill_kernel<<<(out_size + 1023) / 1024, 1024, 0, stream>>>(out, 2000000, out_size);
    return;
  }

  int*    hist = (int*)((char*)d_ws + o_hist);
  int*    off  = (int*)((char*)d_ws + o_off);
  int*    cur  = (int*)((char*)d_ws + o_cur);
  float2* emb  = (float2*)((char*)d_ws + o_emb);
  int2*   pk   = (int2*)((char*)d_ws + o_pk);

  hipMemsetAsync(hist, 0, hist_bytes, stream);
  hist_kernel<<<(BATCH * NPIX) / 256, 256, 0, stream>>>(in, out, hist);
  scan_kernel<<<BATCH, 1024, 0, stream>>>(hist, off, cur);
  scatter_kernel<<<(BATCH * NPIX) / 256, 256, 0, stream>>>(in, cur, emb, pk);
  cluster_kernel<<<BATCH, 1024, 0, stream>>>(in, out, emb, pk, off);
}

// Round 9
// 945.238 us; speedup vs baseline: 3.7412x; 1.0830x over previous
//
#include <hip/hip_runtime.h>
#include <math.h>

#define BATCH 4
#define HH 512
#define WW 1024
#define NPIX (HH*WW)          // 524288 = 2^19
#define CCAP 196608           // compaction capacity per image (expected ~161.7k valid)
#define GX 64
#define GY 48
#define NCELL (GX*GY)         // 3072 cells, 0.0625 x 0.0625 over [-1,3]x[-1,2]
#define CELL 0.0625f
#define INVCELL 16.0f
#define SEGSZ 256             // pixels per argmax-cache segment
#define NSEGMAX (CCAP/SEGSZ)  // 768
#define DLCAP 2048            // dirty-segment list capacity
#define CKCAP 1600            // chunk queue capacity (worst observed ~300)

// ---------------- XLA:CPU f32 math replicas (unchanged from passing rounds) ----
__device__ __forceinline__ float xla_tanhf(float x) {
  if (fabsf(x) < 0.0004f) return x;
  float xc = fminf(fmaxf(x, -7.90531110763549805f), 7.90531110763549805f);
  float x2 = __fmul_rn(xc, xc);
  float p = -2.76076847742355e-16f;
  p = fmaf(x2, p, 2.00018790482477e-13f);
  p = fmaf(x2, p, -8.60467152213735e-11f);
  p = fmaf(x2, p, 5.12229709037114e-08f);
  p = fmaf(x2, p, 1.48572235717979e-05f);
  p = fmaf(x2, p, 6.37261928875436e-04f);
  p = fmaf(x2, p, 4.89352455891786e-03f);
  p = __fmul_rn(xc, p);
  float q = fmaf(x2, 1.19825839466702e-06f, 1.18534705686654e-04f);
  q = fmaf(x2, q, 2.26843463243900e-03f);
  q = fmaf(x2, q, 4.89352518554385e-03f);
  return __fdiv_rn(p, q);
}

__device__ __forceinline__ float xla_expf(float x) {
  float xc = fminf(fmaxf(x, -87.3365478515625f), 88.72283935546875f);
  float m = floorf(fmaf(xc, 1.44269504088896341f, 0.5f));
  float r = fmaf(m, -0.693359375f, xc);
  r = fmaf(m, 2.12194440e-4f, r);
  float r2 = __fmul_rn(r, r);
  float p = 1.9875691500e-4f;
  p = fmaf(p, r, 1.3981999507e-3f);
  p = fmaf(p, r, 8.3334519073e-3f);
  p = fmaf(p, r, 4.1665795894e-2f);
  p = fmaf(p, r, 1.6666665459e-1f);
  p = fmaf(p, r, 5.0000001201e-1f);
  float y = fmaf(r2, p, r);
  y = __fadd_rn(y, 1.0f);
  return ldexpf(y, (int)m);
}

__device__ __forceinline__ float xla_sigmoidf(float x) {
  return fmaf(0.5f, xla_tanhf(__fmul_rn(0.5f, x)), 0.5f);
}

// Proposal test — byte-identical decision logic to the passing kernels.
__device__ __forceinline__ bool prop_test(float2 e, float cx, float cy,
                                          float den0, float den1,
                                          float inv0, float inv1) {
  float d0 = __fsub_rn(e.x, cx), d1 = __fsub_rn(e.y, cy);
  float dd0 = __fmul_rn(d0, d0), dd1 = __fmul_rn(d1, d1);
  float zf = fmaf(dd0, inv0, __fmul_rn(dd1, inv1));
  if (zf < 0.6921472f) return true;
  if (zf <= 0.6941472f) {
    float t0 = __fdiv_rn(dd0, den0);
    float t1 = __fdiv_rn(dd1, den1);
    float z = __fadd_rn(t0, t1);
    return xla_expf(-z) > 0.5f;
  }
  return false;
}

__device__ __forceinline__ int cell_of_x(float ex) {
  int c = (int)((ex + 1.0f) * INVCELL);
  return min(max(c, 0), GX - 1);
}
__device__ __forceinline__ int cell_of_y(float ey) {
  int c = (int)((ey + 1.0f) * INVCELL);
  return min(max(c, 0), GY - 1);
}

// ---------------- kernels ----------------

__global__ __launch_bounds__(1024) void fill_kernel(int* out, int val, int n) {
  int i = blockIdx.x * 1024 + threadIdx.x;
  if (i < n) out[i] = val;
}

// pass A: zero output, LDS-aggregated histogram (one global atomic per block+cell)
__global__ __launch_bounds__(1024) void hist_kernel(const float* __restrict__ in,
                                                    int* __restrict__ out,
                                                    int* __restrict__ hist) {
  __shared__ int lh[NCELL];
  int tid = threadIdx.x;
  int gid = blockIdx.x * 1024 + tid;
  int b = gid >> 19;
  int p = gid & (NPIX - 1);
  for (int j = tid; j < NCELL; j += 1024) lh[j] = 0;
  __syncthreads();
  const float* base = in + (size_t)b * 5 * NPIX;
  float seed = base[(size_t)4 * NPIX + p];
  out[gid] = 0;
  if (seed > 0.5f) {
    float ox = base[p];
    float oy = base[(size_t)NPIX + p];
    int col = p & (WW - 1);
    int row = p >> 10;
    float gx = __fmul_rn((float)col, 2.0f / 1023.0f);
    float gy = __fmul_rn((float)row, 1.0f / 511.0f);
    float ex = __fadd_rn(xla_tanhf(ox), gx);
    float ey = __fadd_rn(xla_tanhf(oy), gy);
    atomicAdd(&lh[cell_of_y(ey) * GX + cell_of_x(ex)], 1);
  }
  __syncthreads();
  for (int j = tid; j < NCELL; j += 1024) {
    int c = lh[j];
    if (c) atomicAdd(&hist[b * NCELL + j], c);
  }
}

// pass B: exclusive scan of the cell counts per image (one block per image)
__global__ __launch_bounds__(1024) void scan_kernel(const int* __restrict__ hist,
                                                    int* __restrict__ off,
                                                    int* __restrict__ cursor) {
  __shared__ int s_c[NCELL];
  __shared__ int s_ps[1024];
  int b = blockIdx.x, t = threadIdx.x;
  const int* h = hist + b * NCELL;
  for (int i = t; i < NCELL; i += 1024) s_c[i] = h[i];
  __syncthreads();
  int a = s_c[3 * t], b2 = s_c[3 * t + 1], c2 = s_c[3 * t + 2];
  int th = a + b2 + c2;
  s_ps[t] = th;
  __syncthreads();
  for (int d = 1; d < 1024; d <<= 1) {
    int v = (t >= d) ? s_ps[t - d] : 0;
    __syncthreads();
    s_ps[t] += v;
    __syncthreads();
  }
  int excl = s_ps[t] - th;
  int* ob = off + b * (NCELL + 1);
  int* cb = cursor + b * NCELL;
  ob[3 * t] = excl;              cb[3 * t] = excl;
  ob[3 * t + 1] = excl + a;      cb[3 * t + 1] = excl + a;
  ob[3 * t + 2] = excl + a + b2; cb[3 * t + 2] = excl + a + b2;
  if (t == 1023) ob[NCELL] = s_ps[1023];
}

// pass C: LDS-aggregated scatter (one global atomic per block+cell). Within-cell
// order is arbitrary — all downstream reductions are order-independent and the
// argmax tiebreak uses the global pixel index.
__global__ __launch_bounds__(1024) void scatter_kernel(const float* __restrict__ in,
                                                       int* __restrict__ cursor,
                                                       float2* __restrict__ emb,
                                                       int2* __restrict__ pk) {
  __shared__ int lh[NCELL];
  __shared__ int lbase[NCELL];
  int tid = threadIdx.x;
  int gid = blockIdx.x * 1024 + tid;
  int b = gid >> 19;
  int p = gid & (NPIX - 1);
  for (int j = tid; j < NCELL; j += 1024) lh[j] = 0;
  __syncthreads();
  const float* base = in + (size_t)b * 5 * NPIX;
  float seed = base[(size_t)4 * NPIX + p];
  bool valid = seed > 0.5f;
  float ex = 0.0f, ey = 0.0f, smv = 0.0f;
  int cell = 0, sl = 0;
  if (valid) {
    float ox = base[p];
    float oy = base[(size_t)NPIX + p];
    int col = p & (WW - 1);
    int row = p >> 10;
    float gx = __fmul_rn((float)col, 2.0f / 1023.0f);
    float gy = __fmul_rn((float)row, 1.0f / 511.0f);
    ex = __fadd_rn(xla_tanhf(ox), gx);
    ey = __fadd_rn(xla_tanhf(oy), gy);
    smv = xla_sigmoidf(seed);
    cell = cell_of_y(ey) * GX + cell_of_x(ex);
    sl = atomicAdd(&lh[cell], 1);
  }
  __syncthreads();
  for (int j = tid; j < NCELL; j += 1024) {
    int c = lh[j];
    if (c) lbase[j] = atomicAdd(&cursor[b * NCELL + j], c);
  }
  __syncthreads();
  if (valid) {
    int slot = lbase[cell] + sl;
    if (slot < CCAP) {
      emb[(size_t)b * CCAP + slot] = make_float2(ex, ey);
      pk[(size_t)b * CCAP + slot]  = make_int2(__float_as_int(smv), p);
    }
  }
}

// Segment scan helper (unchanged from passing rounds 7/8).
__device__ __forceinline__ void seg_rescan(int s, int V, int lane,
    const unsigned* s_uncl, const int2* __restrict__ pk,
    const float2* __restrict__ emb, const float* __restrict__ base,
    unsigned long long* s_segkey, int* s_segci, float4* s_segaux,
    bool checkAlive) {
  unsigned long long bk = 0ULL; int bci = -1; int bpx = 0;
  #pragma unroll
  for (int j = 0; j < 4; ++j) {
    int i = (s << 8) + (j << 6) + lane;
    if (i < V) {
      bool alive = !checkAlive || ((s_uncl[i >> 5] >> (i & 31)) & 1u);
      if (alive) {
        int2 v = pk[i];
        unsigned long long k = ((unsigned long long)(unsigned)v.x << 32) | (unsigned)(~v.y);
        if (k > bk) { bk = k; bci = i; bpx = v.y; }
      }
    }
  }
  unsigned long long mk = bk; int mci = bci;
  #pragma unroll
  for (int o = 1; o < 64; o <<= 1) {
    unsigned long long ok = __shfl_xor(mk, o);
    int oci = __shfl_xor(mci, o);
    if (ok > mk) { mk = ok; mci = oci; }
  }
  if (lane == 0) { s_segkey[s] = mk; s_segci[s] = mci; }
  if (mk != 0ULL && bk == mk) {          // unique winner lane
    float2 e = emb[mci];
    float sxv = base[(size_t)2 * NPIX + bpx];
    float syv = base[(size_t)3 * NPIX + bpx];
    float d0 = __fmul_rn(2.0f, __fmul_rn(sxv, sxv));   // ref: 2.0 * s**2
    float d1 = __fmul_rn(2.0f, __fmul_rn(syv, syv));
    s_segaux[s] = make_float4(e.x, e.y, d0, d1);
  }
}

// One workgroup per image. 2 barriers/iteration. Pass-1 work is a flat 128-px
// chunk queue (built redundantly per wave; benign identical-value LDS races)
// consumed round-robin by all 16 waves — removes wave-pair load imbalance.
__global__ __launch_bounds__(1024) void cluster_kernel(const float* __restrict__ in,
                                                       int* __restrict__ out,
                                                       const float2* __restrict__ emb_all,
                                                       const int2* __restrict__ pk_all,
                                                       const int* __restrict__ off_g) {
  __shared__ unsigned int s_uncl[CCAP / 32];            // 24 KB
  __shared__ int s_off[NCELL + 1];                      // 12 KB
  __shared__ unsigned long long s_segkey[NSEGMAX];      // 6 KB
  __shared__ int s_segci[NSEGMAX];                      // 3 KB
  __shared__ float4 s_segaux[NSEGMAX];                  // 12 KB
  __shared__ int s_dlist[DLCAP];                        // 8 KB
  __shared__ int s_ck[CKCAP];                           // 6.4 KB
  __shared__ int4 s_row4[24];                           // 384 B
  __shared__ int s_pc[2];
  __shared__ int s_uc[2];
  __shared__ int s_nd[2];

  int b = blockIdx.x;
  int tid = threadIdx.x;
  int lane = tid & 63;
  int wid = tid >> 6;
  const int* offb = off_g + b * (NCELL + 1);
  int V = offb[NCELL];
  const float2* emb = emb_all + (size_t)b * CCAP;
  const int2*   pk  = pk_all  + (size_t)b * CCAP;
  int* outb = out + (size_t)b * NPIX;
  const float* base = in + (size_t)b * 5 * NPIX;

  if (V > CCAP) {   // capacity overflow marker
    for (int i = tid; i < NPIX; i += 1024) outb[i] = 1000000;
    return;
  }
  int NSEG = (V + SEGSZ - 1) >> 8;

  for (int i = tid; i <= NCELL; i += 1024) s_off[i] = offb[i];
  for (int w = tid; w < CCAP / 32; w += 1024) {
    int basebit = w << 5;
    unsigned m;
    if (basebit + 32 <= V)      m = 0xffffffffu;
    else if (basebit >= V)      m = 0u;
    else                        m = (1u << (V - basebit)) - 1u;
    s_uncl[w] = m;
  }
  if (tid < 2) { s_pc[tid] = 0; s_uc[tid] = 0; s_nd[tid] = 0; }
  __syncthreads();

  // build segment caches (all pixels alive)
  for (int s = wid; s < NSEG; s += 16)
    seg_rescan(s, V, lane, s_uncl, pk, emb, base, s_segkey, s_segci, s_segaux, false);
  __syncthreads();

  int ucount = V, count = 1, guard = 0;
  int t = 0;
  while (ucount > 64 && guard++ <= CCAP) {
    int cur = t & 1, nxt = cur ^ 1;

    // ---- wave-redundant argmax: key-only shfl reduce + ballot recovery ----
    unsigned long long lk = 0ULL; int lsg = -1;
    for (int s = lane; s < NSEG; s += 64) {
      unsigned long long v = s_segkey[s];
      if (v > lk) { lk = v; lsg = s; }
    }
    unsigned long long gk = lk;
    #pragma unroll
    for (int o = 1; o < 64; o <<= 1) {
      unsigned long long ok = __shfl_xor(gk, o);
      if (ok > gk) gk = ok;
    }
    if (gk == 0ULL) break;
    float sm = __uint_as_float((unsigned)(gk >> 32));
    if (sm < 0.5f) break;              // ref's new_done (provably never fires)
    unsigned long long bmask = __ballot(lk == gk);   // keys unique -> one lane
    int src = __builtin_ctzll(bmask);
    int sg = __shfl(lsg, src);

    float4 aux = s_segaux[sg];         // broadcast LDS read
    float cx = aux.x, cy = aux.y, den0 = aux.z, den1 = aux.w;
    float inv0 = 1.0f / den0;
    float inv1 = 1.0f / den1;
    float ry = sqrtf(__fmul_rn(den1, 0.6971472f)) * 1.00001f;
    int r0 = cell_of_y(cy - ry);
    int r1 = cell_of_y(cy + ry);
    int nr = r1 - r0 + 1;              // <= 19

    // ---- per-lane row geometry + chunk queue build (redundant per wave) ----
    int ck = 0, rs_l = 0, re_l = 0, m0_l = 0, m1_l = 0;
    if (lane < nr) {
      int r = r0 + lane;
      float ylo = fmaf((float)r, CELL, -1.0f);
      float dy = fmaxf(0.0f, fmaxf(ylo - cy, cy - (ylo + CELL))) * 0.999999f;
      float rem = 0.6971472f - dy * dy * inv1;
      if (rem > 0.0f) {
        float dxm = sqrtf(den0 * rem) * 1.00001f;
        int c0 = cell_of_x(cx - dxm), c1 = cell_of_x(cx + dxm);
        int rbase = r * GX;
        rs_l = s_off[rbase + c0]; re_l = s_off[rbase + c1 + 1];
        m0_l = rs_l; m1_l = rs_l;
        float dyc = fmaxf(fabsf(ylo - cy), fabsf(ylo + CELL - cy)) + 1e-5f;
        float remI = 0.6920f - dyc * dyc * inv1;
        if (remI > 0.0f) {
          float dxin = sqrtf(den0 * remI) * 0.9999f;
          int a  = (int)ceilf(fmaf(cx - dxin, INVCELL, INVCELL) + 1e-3f);
          int bb = (int)floorf(fmaf(cx + dxin, INVCELL, INVCELL) - 1e-3f) - 1;
          a = max(a, c0); bb = min(bb, c1);
          if (a <= bb) { m0_l = s_off[rbase + a]; m1_l = s_off[rbase + bb + 1]; }
        }
        ck = (re_l - rs_l + 127) >> 7;
      }
    }
    int cum = ck;                       // 5-step prefix over lanes 0..31 (nr<=19)
    #pragma unroll
    for (int o = 1; o < 32; o <<= 1) {
      int u = __shfl_up(cum, o);
      if (lane >= o) cum += u;
    }
    int nc = __shfl(cum, 31);
    int excl = cum - ck;
    if (lane < nr && ck) {
      s_row4[lane] = make_int4(m0_l, m1_l, re_l, 0);
      for (int k = 0; k < ck; ++k)
        s_ck[excl + k] = (lane << 24) | (rs_l + (k << 7));
    }

    // ---- pass 1: chunk queue, all waves round-robin ----
    int pc = 0, uc = 0;
    for (int c = wid; c < nc; c += 16) {
      int e = s_ck[c];
      int rl = e >> 24;
      int i0 = e & 0xffffff;
      int4 rw = s_row4[rl];             // m0, m1, re
      int hi = min(i0 + 128, rw.z);
      int i = i0 + lane, i2 = i + 64;
      bool p0, p1;
      if (i0 >= rw.x && i0 + 128 <= rw.y) {   // fully-interior chunk: no loads
        p0 = i < hi; p1 = i2 < hi;
      } else {
        p0 = (i < hi) && ((i >= rw.x && i < rw.y) ||
                          prop_test(emb[i], cx, cy, den0, den1, inv0, inv1));
        p1 = (i2 < hi) && ((i2 >= rw.x && i2 < rw.y) ||
                           prop_test(emb[i2], cx, cy, den0, den1, inv0, inv1));
      }
      unsigned long long bm0 = __ballot(p0);
      unsigned long long bm1 = __ballot(p1);
      if ((bm0 | bm1) == 0ULL) continue;
      int off = i0 & 31;
      unsigned w = (unsigned)(i0 >> 5);
      unsigned bits = 0; unsigned tw = w;
      if (lane == 0)      { pc += (int)__popcll(bm0); bits = (unsigned)(bm0 << off); tw = w; }
      else if (lane == 1) { bits = (unsigned)(bm0 >> (32 - off)); tw = w + 1; }
      else if (lane == 2) { if (off > 0) bits = (unsigned)(bm0 >> (64 - off)); tw = w + 2; }
      else if (lane == 3) { pc += (int)__popcll(bm1); bits = (unsigned)(bm1 << off); tw = w + 2; }
      else if (lane == 4) { bits = (unsigned)(bm1 >> (32 - off)); tw = w + 3; }
      else if (lane == 5) { if (off > 0) bits = (unsigned)(bm1 >> (64 - off)); tw = w + 4; }
      if (bits) {
        unsigned old = atomicAnd(&s_uncl[tw], ~bits);
        unsigned remv = old & bits;
        if (remv) {
          uc += __popc(remv);
          int seg = (int)(tw >> 3);           // 256 px = 8 words
          int ciw = s_segci[seg];
          if ((ciw >> 5) == (int)tw && ((remv >> (ciw & 31)) & 1u)) {
            int pos = atomicAdd(&s_nd[cur], 1);
            if (pos < DLCAP) s_dlist[pos] = seg;
          }
        }
      }
    }
    for (int o = 32; o > 0; o >>= 1) {
      pc += __shfl_down(pc, o);
      uc += __shfl_down(uc, o);
    }
    if (lane == 0 && (pc | uc)) {
      if (pc) atomicAdd(&s_pc[cur], pc);
      if (uc) atomicAdd(&s_uc[cur], uc);
    }
    __syncthreads();   // B1

    int pcT = s_pc[cur];
    int ucR = s_uc[cur];            // total removed this iter (includes seed)
    int ndRaw = s_nd[cur];
    bool accept = (pcT > 64) && (2 * (ucR - 1) > pcT);  // ref uc excludes seed
    int label = count & 255;
    if (accept) count++;
    ucount -= ucR;
    if (tid == 0) { s_pc[nxt] = 0; s_uc[nxt] = 0; s_nd[nxt] = 0; }

    // ---- labels (rare: only accepted iterations) — reuse chunk queue ----
    if (accept) {
      for (int c = wid; c < nc; c += 16) {
        int e = s_ck[c];
        int rl = e >> 24;
        int i0 = e & 0xffffff;
        int4 rw = s_row4[rl];
        int hi = min(i0 + 128, rw.z);
        int i = i0 + lane, i2 = i + 64;
        if (i < hi && ((i >= rw.x && i < rw.y) ||
                       prop_test(emb[i], cx, cy, den0, den1, inv0, inv1)))
          outb[pk[i].y] = label;
        if (i2 < hi && ((i2 >= rw.x && i2 < rw.y) ||
                        prop_test(emb[i2], cx, cy, den0, den1, inv0, inv1)))
          outb[pk[i2].y] = label;
      }
    }

    // ---- rescans: only segments whose cached winner was removed ----
    if (ndRaw > DLCAP) {
      for (int s = wid; s < NSEG; s += 16)
        seg_rescan(s, V, lane, s_uncl, pk, emb, base, s_segkey, s_segci, s_segaux, true);
    } else {
      for (int d = wid; d < ndRaw; d += 16)
        seg_rescan(s_dlist[d], V, lane, s_uncl, pk, emb, base, s_segkey, s_segci, s_segaux, true);
    }
    __syncthreads();   // B2
    t++;
  }
}

// ---------------- launch ----------------

extern "C" void kernel_launch(void* const* d_in, const int* in_sizes, int n_in,
                              void* d_out, int out_size, void* d_ws, size_t ws_size,
                              hipStream_t stream) {
  const float* in = (const float*)d_in[0];
  int* out = (int*)d_out;

  size_t hist_bytes = (size_t)BATCH * NCELL * sizeof(int);
  size_t off_bytes  = (size_t)BATCH * (NCELL + 1) * sizeof(int);
  size_t cur_bytes  = (size_t)BATCH * NCELL * sizeof(int);
  size_t emb_bytes  = (size_t)BATCH * CCAP * sizeof(float2);
  size_t pk_bytes   = (size_t)BATCH * CCAP * sizeof(int2);

  size_t o_hist = 256;
  size_t o_off  = (o_hist + hist_bytes + 255) & ~(size_t)255;
  size_t o_cur  = (o_off + off_bytes + 255) & ~(size_t)255;
  size_t o_emb  = (o_cur + cur_bytes + 255) & ~(size_t)255;
  size_t o_pk   = (o_emb + emb_bytes + 255) & ~(size_t)255;
  size_t need   = o_pk + pk_bytes;

  if (ws_size < need) {
    fill_kernel<<<(out_size + 1023) / 1024, 1024, 0, stream>>>(out, 2000000, out_size);
    return;
  }

  int*    hist = (int*)((char*)d_ws + o_hist);
  int*    off  = (int*)((char*)d_ws + o_off);
  int*    cur  = (int*)((char*)d_ws + o_cur);
  float2* emb  = (float2*)((char*)d_ws + o_emb);
  int2*   pk   = (int2*)((char*)d_ws + o_pk);

  hipMemsetAsync(hist, 0, hist_bytes, stream);
  hist_kernel<<<(BATCH * NPIX) / 1024, 1024, 0, stream>>>(in, out, hist);
  scan_kernel<<<BATCH, 1024, 0, stream>>>(hist, off, cur);
  scatter_kernel<<<(BATCH * NPIX) / 1024, 1024, 0, stream>>>(in, cur, emb, pk);
  cluster_kernel<<<BATCH, 1024, 0, stream>>>(in, out, emb, pk, off);
}